// Round 2
// baseline (11878.376 us; speedup 1.0000x reference)
//
#include <hip/hip_runtime.h>
#include <math.h>

#define N_NODES   20000
#define N_EDGESC  320000
#define N_ANGLESC 640000
#define N_GRAPHSC 256
#define NFDIM     92
#define EFDIM     40
#define FCDIM     256

typedef unsigned short u16;

__device__ __forceinline__ float softplusf_(float x) {
  return fmaxf(x, 0.f) + log1pf(expf(-fabsf(x)));
}
__device__ __forceinline__ float sigmoidf_(float x) {
  return 1.f / (1.f + expf(-x));
}
__device__ __forceinline__ u16 f2bf(float x) {
  union { float f; unsigned u; } v; v.f = x;
  unsigned r = v.u + 0x7fff + ((v.u >> 16) & 1);
  return (u16)(r >> 16);
}
__device__ __forceinline__ float bf2f(u16 h) {
  union { unsigned u; float f; } v; v.u = ((unsigned)h) << 16; return v.f;
}

// ---------------- fused bondlen + RBF: ef[e][k] = exp(-(39/8)*(|r_e|-c_k)^2) ----------------
__global__ void k_rbf_edge(const float* __restrict__ r, float* __restrict__ ef) {
  int e = blockIdx.x * blockDim.x + threadIdx.x;
  if (e >= N_EDGESC) return;
  float x = r[e * 3 + 0], y = r[e * 3 + 1], z = r[e * 3 + 2];
  float bl = sqrtf(x * x + y * y + z * z);
  const float step = 8.f / 39.f;
  const float g = 39.f / 8.f;
  float4* o = (float4*)(ef + (long long)e * EFDIM);
#pragma unroll
  for (int i = 0; i < 10; i++) {
    float4 v;
    float d0 = bl - (4 * i + 0) * step; v.x = expf(-g * d0 * d0);
    float d1 = bl - (4 * i + 1) * step; v.y = expf(-g * d1 * d1);
    float d2 = bl - (4 * i + 2) * step; v.z = expf(-g * d2 * d2);
    float d3 = bl - (4 * i + 3) * step; v.w = expf(-g * d3 * d3);
    o[i] = v;
  }
}

// ---------------- generic small GEMM + bias: C[M,N] = A[M,K] @ W[K,N] + b ----------------
__global__ void k_gemm_bias(const float* __restrict__ A, const float* __restrict__ W,
                            const float* __restrict__ b, float* __restrict__ C,
                            int M, int N, int K) {
  int idx = blockIdx.x * blockDim.x + threadIdx.x;
  int total = M * N;
  if (idx >= total) return;
  int row = idx / N, col = idx - row * N;
  const float* a = A + (long long)row * K;
  float acc = b[col];
#pragma unroll 4
  for (int k = 0; k < K; k++) acc += a[k] * W[k * N + col];
  C[idx] = acc;
}

// ---------------- c1 message: mT[c][e] = hs[src[e]][c] + hd[dst[e]][c] + ef[e]@We[:,c] + be[c]
__global__ __launch_bounds__(256) void k_edge_m1(
    const float* __restrict__ hs, const float* __restrict__ hd,
    const float* __restrict__ ef, const int* __restrict__ src, const int* __restrict__ dst,
    const float* __restrict__ We, const float* __restrict__ be, u16* __restrict__ mT) {
  int e = blockIdx.x * blockDim.x + threadIdx.x;
  if (e >= N_EDGESC) return;
  float efr[40];
  {
    const float4* e4 = (const float4*)(ef + (long long)e * EFDIM);
#pragma unroll
    for (int i = 0; i < 10; i++) {
      float4 v = e4[i];
      efr[4 * i] = v.x; efr[4 * i + 1] = v.y; efr[4 * i + 2] = v.z; efr[4 * i + 3] = v.w;
    }
  }
  const float* hsr = hs + (long long)src[e] * (2 * NFDIM);
  const float* hdr = hd + (long long)dst[e] * (2 * NFDIM);
  for (int c4 = 0; c4 < 46; c4++) {
    int c = c4 * 4;
    float4 acc = *(const float4*)(be + c);
    float4 a = *(const float4*)(hsr + c);
    float4 bb = *(const float4*)(hdr + c);
    acc.x += a.x + bb.x; acc.y += a.y + bb.y; acc.z += a.z + bb.z; acc.w += a.w + bb.w;
#pragma unroll
    for (int k = 0; k < 40; k++) {
      float4 w = *(const float4*)(We + k * (2 * NFDIM) + c);
      float ek = efr[k];
      acc.x += ek * w.x; acc.y += ek * w.y; acc.z += ek * w.z; acc.w += ek * w.w;
    }
    mT[(long long)(c + 0) * N_EDGESC + e] = f2bf(acc.x);
    mT[(long long)(c + 1) * N_EDGESC + e] = f2bf(acc.y);
    mT[(long long)(c + 2) * N_EDGESC + e] = f2bf(acc.z);
    mT[(long long)(c + 3) * N_EDGESC + e] = f2bf(acc.w);
  }
}

// ---------------- c2 message (line graph), angle RBF computed inline ----------------
__global__ __launch_bounds__(256) void k_angle_m2(
    const float* __restrict__ ef, const float* __restrict__ angle_h,
    const int* __restrict__ src, const int* __restrict__ dst,
    const float* __restrict__ Ws, const float* __restrict__ bs,
    const float* __restrict__ Wd, const float* __restrict__ bd,
    const float* __restrict__ We, const float* __restrict__ be,
    u16* __restrict__ mT) {
  int a = blockIdx.x * blockDim.x + threadIdx.x;
  if (a >= N_ANGLESC) return;
  float xs[40], xd[40], xa[40];
  {
    const float4* p = (const float4*)(ef + (long long)src[a] * EFDIM);
    const float4* q = (const float4*)(ef + (long long)dst[a] * EFDIM);
#pragma unroll
    for (int i = 0; i < 10; i++) {
      float4 v = p[i]; xs[4 * i] = v.x; xs[4 * i + 1] = v.y; xs[4 * i + 2] = v.z; xs[4 * i + 3] = v.w;
      float4 u = q[i]; xd[4 * i] = u.x; xd[4 * i + 1] = u.y; xd[4 * i + 2] = u.z; xd[4 * i + 3] = u.w;
    }
    const float PI = 3.14159265358979323846f;
    const float step = PI / 39.f;
    const float g = 39.f / PI;
    float h = angle_h[a];
#pragma unroll
    for (int k = 0; k < 40; k++) {
      float d = h - (-PI * 0.5f + k * step);
      xa[k] = expf(-g * d * d);
    }
  }
  for (int c4 = 0; c4 < 20; c4++) {
    int c = c4 * 4;
    float4 b1 = *(const float4*)(bs + c);
    float4 b2 = *(const float4*)(bd + c);
    float4 b3 = *(const float4*)(be + c);
    float4 acc;
    acc.x = b1.x + b2.x + b3.x; acc.y = b1.y + b2.y + b3.y;
    acc.z = b1.z + b2.z + b3.z; acc.w = b1.w + b2.w + b3.w;
#pragma unroll
    for (int k = 0; k < 40; k++) {
      float4 w1 = *(const float4*)(Ws + k * (2 * EFDIM) + c);
      float4 w2 = *(const float4*)(Wd + k * (2 * EFDIM) + c);
      float4 w3 = *(const float4*)(We + k * (2 * EFDIM) + c);
      float s = xs[k], d = xd[k], aa = xa[k];
      acc.x += s * w1.x + d * w2.x + aa * w3.x;
      acc.y += s * w1.y + d * w2.y + aa * w3.y;
      acc.z += s * w1.z + d * w2.z + aa * w3.z;
      acc.w += s * w1.w + d * w2.w + aa * w3.w;
    }
    mT[(long long)(c + 0) * N_ANGLESC + a] = f2bf(acc.x);
    mT[(long long)(c + 1) * N_ANGLESC + a] = f2bf(acc.y);
    mT[(long long)(c + 2) * N_ANGLESC + a] = f2bf(acc.z);
    mT[(long long)(c + 3) * N_ANGLESC + a] = f2bf(acc.w);
  }
}

// ---------------- column stats on transposed bf16 [C][R] buffer ----------------
// R/chunks must be a multiple of 4.
__global__ void k_colstats_Tb(const u16* __restrict__ X, int R, int chunks, int C,
                              float* __restrict__ stat) {
  int col = blockIdx.x / chunks;
  int chunk = blockIdx.x - col * chunks;
  if (col >= C) return;
  int per = R / chunks;
  const u16* x = X + (long long)col * R + (long long)chunk * per;
  float s = 0.f, q = 0.f;
  for (int i = threadIdx.x * 4; i < per; i += blockDim.x * 4) {
    ushort4 v = *(const ushort4*)(x + i);
    float a = bf2f(v.x), b = bf2f(v.y), c = bf2f(v.z), d = bf2f(v.w);
    s += a + b + c + d;
    q += a * a + b * b + c * c + d * d;
  }
  for (int off = 32; off > 0; off >>= 1) {
    s += __shfl_down(s, off, 64);
    q += __shfl_down(q, off, 64);
  }
  __shared__ float ls[2][4];
  int wid = threadIdx.x >> 6;
  if ((threadIdx.x & 63) == 0) { ls[0][wid] = s; ls[1][wid] = q; }
  __syncthreads();
  if (threadIdx.x == 0) {
    float S = 0.f, Q = 0.f;
    int nw = blockDim.x >> 6;
    for (int w = 0; w < nw; w++) { S += ls[0][w]; Q += ls[1][w]; }
    atomicAdd(&stat[col], S);
    atomicAdd(&stat[C + col], Q);
  }
}

// ---------------- column stats on row-major [R][C], C <= blockDim ----------------
__global__ void k_colstats_rm(const float* __restrict__ X, int R, int C,
                              float* __restrict__ stat) {
  int c = threadIdx.x;
  if (c >= C) return;
  float s = 0.f, q = 0.f;
  for (int rr = blockIdx.x; rr < R; rr += gridDim.x) {
    float v = X[(long long)rr * C + c];
    s += v; q += v * v;
  }
  atomicAdd(&stat[c], s);
  atomicAdd(&stat[C + c], q);
}

// ---------------- BN finalize: scale/shift per column ----------------
__global__ void k_finalize(const float* __restrict__ stat, const float* __restrict__ g,
                           const float* __restrict__ b, float* __restrict__ scsh,
                           int C, float invR) {
  int c = threadIdx.x + blockIdx.x * blockDim.x;
  if (c >= C) return;
  float mu = stat[c] * invR;
  float var = stat[C + c] * invR - mu * mu;
  float is = rsqrtf(var + 1e-5f);
  float sc = g[c] * is;
  scsh[c] = sc;
  scsh[C + c] = b[c] - mu * sc;
}

// ---------------- apply BN + gated act + scatter-sum (atomics) ----------------
template <int F2, int F, int E>
__global__ __launch_bounds__(256) void k_apply_scatter_T(
    const u16* __restrict__ mT, const int* __restrict__ dstIdx,
    const float* __restrict__ scsh, float* __restrict__ hagg) {
  long long idx = (long long)blockIdx.x * blockDim.x + threadIdx.x;
  constexpr long long total = (long long)F * E;
  if (idx >= total) return;
  int c = (int)(idx / E), e = (int)(idx - (long long)c * E);
  float mf = bf2f(mT[idx]);
  float ms = bf2f(mT[idx + total]);
  mf = mf * scsh[c] + scsh[F2 + c];
  ms = ms * scsh[F + c] + scsh[F2 + F + c];
  float gated = sigmoidf_(mf) * softplusf_(ms);
  atomicAdd(&hagg[(long long)dstIdx[e] * F + c], gated);
}

// ---------------- residual: out = softplus(xin + hagg*sc + sh), in-place safe ----------------
__global__ void k_bn_residual(const float* __restrict__ xin, const float* __restrict__ hagg,
                              const float* __restrict__ scsh, float* __restrict__ out,
                              int total, int C) {
  int idx = blockIdx.x * blockDim.x + threadIdx.x;
  if (idx >= total) return;
  int c = idx % C;
  out[idx] = softplusf_(xin[idx] + hagg[idx] * scsh[c] + scsh[C + c]);
}

// ---------------- graph average pooling (sums + counts) ----------------
__global__ void k_pool(const float* __restrict__ nf, const int* __restrict__ gid,
                       float* __restrict__ sums, float* __restrict__ cnt) {
  int idx = blockIdx.x * blockDim.x + threadIdx.x;
  constexpr int total = N_NODES * NFDIM;
  if (idx >= total) return;
  int n = idx / NFDIM, c = idx - n * NFDIM;
  int g = gid[n];
  atomicAdd(&sums[g * NFDIM + c], nf[idx]);
  if (c == 0) atomicAdd(&cnt[g], 1.f);
}

// ---------------- head MLP: one block per graph ----------------
__global__ __launch_bounds__(256) void k_head(
    const float* __restrict__ sums, const float* __restrict__ cnt,
    const float* __restrict__ fcW, const float* __restrict__ fcb,
    const float* __restrict__ outW, const float* __restrict__ outb,
    float* __restrict__ out) {
  __shared__ float feats[NFDIM];
  __shared__ float warpsum[4];
  int g = blockIdx.x, t = threadIdx.x;
  if (t < NFDIM) {
    float c = fmaxf(cnt[g], 1.f);
    feats[t] = softplusf_(sums[g * NFDIM + t] / c);
  }
  __syncthreads();
  float acc = fcb[t];
#pragma unroll 4
  for (int k = 0; k < NFDIM; k++) acc += feats[k] * fcW[k * FCDIM + t];
  float z = softplusf_(softplusf_(acc));
  float v = z * outW[t];
  for (int off = 32; off > 0; off >>= 1) v += __shfl_down(v, off, 64);
  if ((t & 63) == 0) warpsum[t >> 6] = v;
  __syncthreads();
  if (t == 0) out[g] = warpsum[0] + warpsum[1] + warpsum[2] + warpsum[3] + outb[0];
}

// ---------------- diagnostic sentinel ----------------
__global__ void k_sentinel(float* out, float v) {
  int i = blockIdx.x * blockDim.x + threadIdx.x;
  if (i < N_GRAPHSC) out[i] = v;
}

static inline int cdiv(long long a, long long b) { return (int)((a + b - 1) / b); }

extern "C" void kernel_launch(void* const* d_in, const int* in_sizes, int n_in,
                              void* d_out, int out_size, void* d_ws, size_t ws_size,
                              hipStream_t stream) {
  (void)in_sizes; (void)n_in; (void)out_size;
  const float* atom_features = (const float*)d_in[0];
  const float* r             = (const float*)d_in[1];
  const float* angle_h       = (const float*)d_in[2];
  const int*   g_src         = (const int*)d_in[3];
  const int*   g_dst         = (const int*)d_in[4];
  const int*   lg_src        = (const int*)d_in[5];
  const int*   lg_dst        = (const int*)d_in[6];
  const int*   node_gid      = (const int*)d_in[7];
  const float* emb_W         = (const float*)d_in[8];
  const float* emb_b         = (const float*)d_in[9];
  const float* c1_Wsrc       = (const float*)d_in[10];
  const float* c1_bsrc       = (const float*)d_in[11];
  const float* c1_Wdst       = (const float*)d_in[12];
  const float* c1_bdst       = (const float*)d_in[13];
  const float* c1_Wedge      = (const float*)d_in[14];
  const float* c1_bedge      = (const float*)d_in[15];
  const float* c1_bnm_g      = (const float*)d_in[16];
  const float* c1_bnm_b      = (const float*)d_in[17];
  const float* c1_bn_g       = (const float*)d_in[18];
  const float* c1_bn_b       = (const float*)d_in[19];
  const float* c2_Wsrc       = (const float*)d_in[20];
  const float* c2_bsrc       = (const float*)d_in[21];
  const float* c2_Wdst       = (const float*)d_in[22];
  const float* c2_bdst       = (const float*)d_in[23];
  const float* c2_Wedge      = (const float*)d_in[24];
  const float* c2_bedge      = (const float*)d_in[25];
  const float* c2_bnm_g      = (const float*)d_in[26];
  const float* c2_bnm_b      = (const float*)d_in[27];
  const float* c2_bn_g       = (const float*)d_in[28];
  const float* c2_bn_b       = (const float*)d_in[29];
  const float* fc_W          = (const float*)d_in[30];
  const float* fc_b          = (const float*)d_in[31];
  const float* out_W         = (const float*)d_in[32];
  const float* out_b         = (const float*)d_in[33];

  // ---- workspace layout (byte-based, 256B-aligned chunks) ----
  char* base = (char*)d_ws;
  size_t off = 0;
  auto walloc = [&](size_t bytes) {
    char* p = base + off;
    off += (bytes + 255) & ~(size_t)255;
    return p;
  };
  u16*   MT    = (u16*)walloc((size_t)58880000 * 2);   // bf16 message buffer (shared c1/c2): 117.76 MB
  float* EF    = (float*)walloc((size_t)12800000 * 4); // edge features (in-place): 51.2 MB
  float* NF    = (float*)walloc((size_t)1840000 * 4);  // node features (in-place): 7.36 MB
  float* HS1   = (float*)walloc((size_t)3680000 * 4);  // h_src table: 14.72 MB
  float* HD1   = (float*)walloc((size_t)3680000 * 4);  // h_dst table: 14.72 MB
  float* HAGG1 = (float*)walloc((size_t)1840000 * 4);  // node agg: 7.36 MB
  float* HAGG2 = (float*)walloc((size_t)12800000 * 4); // edge agg: 51.2 MB
  float* SUMS  = (float*)walloc(23552 * 4);            // pooled sums
  float* CNT   = (float*)walloc(256 * 4);
  float* STAT  = (float*)walloc(512 * 4);
  float* SCSHM = (float*)walloc(1024 * 4);
  float* SCSHN = (float*)walloc(512 * 4);
  if (ws_size < off) {
    // diagnostic: report ws_size in MiB via the output so the failure absmax tells us the budget
    k_sentinel<<<1, 256, 0, stream>>>((float*)d_out, (float)(ws_size >> 20));
    return;
  }

  // features
  k_rbf_edge<<<cdiv(N_EDGESC, 256), 256, 0, stream>>>(r, EF);
  k_gemm_bias<<<cdiv((long long)N_NODES * NFDIM, 256), 256, 0, stream>>>(
      atom_features, emb_W, emb_b, NF, N_NODES, NFDIM, NFDIM);

  for (int i = 0; i < 3; i++) {
    // ---------- conv1 (atom graph) ----------
    k_gemm_bias<<<cdiv((long long)N_NODES * 2 * NFDIM, 256), 256, 0, stream>>>(
        NF, c1_Wsrc + i * NFDIM * 2 * NFDIM, c1_bsrc + i * 2 * NFDIM, HS1, N_NODES, 2 * NFDIM, NFDIM);
    k_gemm_bias<<<cdiv((long long)N_NODES * 2 * NFDIM, 256), 256, 0, stream>>>(
        NF, c1_Wdst + i * NFDIM * 2 * NFDIM, c1_bdst + i * 2 * NFDIM, HD1, N_NODES, 2 * NFDIM, NFDIM);
    k_edge_m1<<<cdiv(N_EDGESC, 256), 256, 0, stream>>>(
        HS1, HD1, EF, g_src, g_dst, c1_Wedge + i * EFDIM * 2 * NFDIM, c1_bedge + i * 2 * NFDIM, MT);
    hipMemsetAsync(STAT, 0, 512 * sizeof(float), stream);
    k_colstats_Tb<<<184 * 8, 256, 0, stream>>>(MT, N_EDGESC, 8, 184, STAT);
    k_finalize<<<1, 256, 0, stream>>>(STAT, c1_bnm_g + i * 184, c1_bnm_b + i * 184, SCSHM, 184, 1.f / N_EDGESC);
    hipMemsetAsync(HAGG1, 0, (size_t)1840000 * sizeof(float), stream);
    k_apply_scatter_T<184, 92, N_EDGESC><<<cdiv((long long)92 * N_EDGESC, 256), 256, 0, stream>>>(
        MT, g_dst, SCSHM, HAGG1);
    hipMemsetAsync(STAT, 0, 512 * sizeof(float), stream);
    k_colstats_rm<<<512, 128, 0, stream>>>(HAGG1, N_NODES, 92, STAT);
    k_finalize<<<1, 256, 0, stream>>>(STAT, c1_bn_g + i * 92, c1_bn_b + i * 92, SCSHN, 92, 1.f / N_NODES);
    k_bn_residual<<<cdiv((long long)N_NODES * NFDIM, 256), 256, 0, stream>>>(
        NF, HAGG1, SCSHN, NF, N_NODES * NFDIM, NFDIM);

    // ---------- conv2 (line graph) ----------
    k_angle_m2<<<cdiv(N_ANGLESC, 256), 256, 0, stream>>>(
        EF, angle_h, lg_src, lg_dst,
        c2_Wsrc + i * EFDIM * 2 * EFDIM, c2_bsrc + i * 2 * EFDIM,
        c2_Wdst + i * EFDIM * 2 * EFDIM, c2_bdst + i * 2 * EFDIM,
        c2_Wedge + i * EFDIM * 2 * EFDIM, c2_bedge + i * 2 * EFDIM, MT);
    hipMemsetAsync(STAT, 0, 512 * sizeof(float), stream);
    k_colstats_Tb<<<80 * 16, 256, 0, stream>>>(MT, N_ANGLESC, 16, 80, STAT);
    k_finalize<<<1, 256, 0, stream>>>(STAT, c2_bnm_g + i * 80, c2_bnm_b + i * 80, SCSHM, 80, 1.f / N_ANGLESC);
    hipMemsetAsync(HAGG2, 0, (size_t)12800000 * sizeof(float), stream);
    k_apply_scatter_T<80, 40, N_ANGLESC><<<cdiv((long long)40 * N_ANGLESC, 256), 256, 0, stream>>>(
        MT, lg_dst, SCSHM, HAGG2);
    hipMemsetAsync(STAT, 0, 512 * sizeof(float), stream);
    k_colstats_rm<<<512, 64, 0, stream>>>(HAGG2, N_EDGESC, 40, STAT);
    k_finalize<<<1, 256, 0, stream>>>(STAT, c2_bn_g + i * 40, c2_bn_b + i * 40, SCSHN, 40, 1.f / N_EDGESC);
    k_bn_residual<<<cdiv((long long)N_EDGESC * EFDIM, 256), 256, 0, stream>>>(
        EF, HAGG2, SCSHN, EF, N_EDGESC * EFDIM, EFDIM);
  }

  // ---------- readout ----------
  hipMemsetAsync(SUMS, 0, (size_t)(23552 + 256) * sizeof(float), stream);  // SUMS + CNT adjacent
  k_pool<<<cdiv((long long)N_NODES * NFDIM, 256), 256, 0, stream>>>(NF, node_gid, SUMS, CNT);
  k_head<<<N_GRAPHSC, 256, 0, stream>>>(SUMS, CNT, fc_W, fc_b, out_W, out_b, (float*)d_out);
}

// Round 3
// 5276.262 us; speedup vs baseline: 2.2513x; 2.2513x over previous
//
#include <hip/hip_runtime.h>
#include <math.h>

#define N_NODES   20000
#define N_EDGESC  320000
#define N_ANGLESC 640000
#define N_GRAPHSC 256
#define NFDIM     92
#define EFDIM     40
#define FCDIM     256

typedef unsigned short u16;

__device__ __forceinline__ float softplusf_(float x) {
  return fmaxf(x, 0.f) + log1pf(expf(-fabsf(x)));
}
__device__ __forceinline__ float sigmoidf_(float x) {
  return 1.f / (1.f + expf(-x));
}
__device__ __forceinline__ u16 f2bf(float x) {
  union { float f; unsigned u; } v; v.f = x;
  unsigned r = v.u + 0x7fff + ((v.u >> 16) & 1);
  return (u16)(r >> 16);
}
__device__ __forceinline__ float bf2f(u16 h) {
  union { unsigned u; float f; } v; v.u = ((unsigned)h) << 16; return v.f;
}

// ================= CSR construction (deterministic) =================
__global__ void k_hist(const int* __restrict__ dst, int E, int* __restrict__ hist) {
  int e = blockIdx.x * blockDim.x + threadIdx.x;
  if (e < E) atomicAdd(&hist[dst[e]], 1);
}

__global__ void k_scan_pass1(const int* __restrict__ hist, int n, int* __restrict__ bsum) {
  __shared__ int buf[256];
  int i = blockIdx.x * 256 + threadIdx.x;
  buf[threadIdx.x] = (i < n) ? hist[i] : 0;
  __syncthreads();
  for (int o = 128; o > 0; o >>= 1) {
    if (threadIdx.x < o) buf[threadIdx.x] += buf[threadIdx.x + o];
    __syncthreads();
  }
  if (threadIdx.x == 0) bsum[blockIdx.x] = buf[0];
}

__global__ void k_scan_partials(int* __restrict__ bsum, int B) {
  __shared__ int buf[256];
  __shared__ int carry;
  if (threadIdx.x == 0) carry = 0;
  __syncthreads();
  for (int base = 0; base < B; base += 256) {
    int i = base + threadIdx.x;
    int v = (i < B) ? bsum[i] : 0;
    buf[threadIdx.x] = v;
    __syncthreads();
    for (int o = 1; o < 256; o <<= 1) {
      int t = (threadIdx.x >= o) ? buf[threadIdx.x - o] : 0;
      __syncthreads();
      buf[threadIdx.x] += t;
      __syncthreads();
    }
    if (i < B) bsum[i] = buf[threadIdx.x] - v + carry;
    int tile_total = buf[255];
    __syncthreads();
    if (threadIdx.x == 0) carry += tile_total;
    __syncthreads();
  }
}

__global__ void k_scan_pass3(const int* __restrict__ hist, int n, int total,
                             const int* __restrict__ bsum,
                             int* __restrict__ offsets, int* __restrict__ cursor) {
  __shared__ int buf[256];
  int i = blockIdx.x * 256 + threadIdx.x;
  int v = (i < n) ? hist[i] : 0;
  buf[threadIdx.x] = v;
  __syncthreads();
  for (int o = 1; o < 256; o <<= 1) {
    int t = (threadIdx.x >= o) ? buf[threadIdx.x - o] : 0;
    __syncthreads();
    buf[threadIdx.x] += t;
    __syncthreads();
  }
  int excl = buf[threadIdx.x] - v + bsum[blockIdx.x];
  if (i < n) {
    offsets[i] = excl;
    cursor[i] = excl;
    if (i == n - 1) offsets[n] = total;
  }
}

__global__ void k_fill(const int* __restrict__ dst, int E,
                       int* __restrict__ cursor, int* __restrict__ perm) {
  int e = blockIdx.x * blockDim.x + threadIdx.x;
  if (e >= E) return;
  int pos = atomicAdd(&cursor[dst[e]], 1);
  perm[pos] = e;
}

__global__ void k_sortbins(const int* __restrict__ offsets, int* __restrict__ perm, int nb) {
  int n = blockIdx.x * blockDim.x + threadIdx.x;
  if (n >= nb) return;
  int lo = offsets[n], hi = offsets[n + 1];
  for (int i = lo + 1; i < hi; i++) {
    int key = perm[i];
    int j = i - 1;
    while (j >= lo && perm[j] > key) { perm[j + 1] = perm[j]; j--; }
    perm[j + 1] = key;
  }
}

// ================= features =================
__global__ void k_rbf_edge(const float* __restrict__ r, float* __restrict__ ef) {
  int e = blockIdx.x * blockDim.x + threadIdx.x;
  if (e >= N_EDGESC) return;
  float x = r[e * 3 + 0], y = r[e * 3 + 1], z = r[e * 3 + 2];
  float bl = sqrtf(x * x + y * y + z * z);
  const float step = 8.f / 39.f;
  const float g = 39.f / 8.f;
  float4* o = (float4*)(ef + (long long)e * EFDIM);
#pragma unroll
  for (int i = 0; i < 10; i++) {
    float4 v;
    float d0 = bl - (4 * i + 0) * step; v.x = expf(-g * d0 * d0);
    float d1 = bl - (4 * i + 1) * step; v.y = expf(-g * d1 * d1);
    float d2 = bl - (4 * i + 2) * step; v.z = expf(-g * d2 * d2);
    float d3 = bl - (4 * i + 3) * step; v.w = expf(-g * d3 * d3);
    o[i] = v;
  }
}

// ================= small GEMM + bias =================
__global__ void k_gemm_bias(const float* __restrict__ A, const float* __restrict__ W,
                            const float* __restrict__ b, float* __restrict__ C,
                            int M, int N, int K) {
  int idx = blockIdx.x * blockDim.x + threadIdx.x;
  int total = M * N;
  if (idx >= total) return;
  int row = idx / N, col = idx - row * N;
  const float* a = A + (long long)row * K;
  float acc = b[col];
#pragma unroll 4
  for (int k = 0; k < K; k++) acc += a[k] * W[k * N + col];
  C[idx] = acc;
}

// ================= c1 message: m[e][c] row-major bf16 =================
__global__ __launch_bounds__(256) void k_edge_m1(
    const float* __restrict__ hs, const float* __restrict__ hd,
    const float* __restrict__ ef, const int* __restrict__ src, const int* __restrict__ dst,
    const float* __restrict__ We, const float* __restrict__ be, u16* __restrict__ m) {
  int e = blockIdx.x * blockDim.x + threadIdx.x;
  if (e >= N_EDGESC) return;
  float efr[40];
  {
    const float4* e4 = (const float4*)(ef + (long long)e * EFDIM);
#pragma unroll
    for (int i = 0; i < 10; i++) {
      float4 v = e4[i];
      efr[4 * i] = v.x; efr[4 * i + 1] = v.y; efr[4 * i + 2] = v.z; efr[4 * i + 3] = v.w;
    }
  }
  const float* hsr = hs + (long long)src[e] * (2 * NFDIM);
  const float* hdr = hd + (long long)dst[e] * (2 * NFDIM);
  u16* row = m + (long long)e * (2 * NFDIM);
  for (int c4 = 0; c4 < 46; c4++) {
    int c = c4 * 4;
    float4 acc = *(const float4*)(be + c);
    float4 a = *(const float4*)(hsr + c);
    float4 bb = *(const float4*)(hdr + c);
    acc.x += a.x + bb.x; acc.y += a.y + bb.y; acc.z += a.z + bb.z; acc.w += a.w + bb.w;
#pragma unroll
    for (int k = 0; k < 40; k++) {
      float4 w = *(const float4*)(We + k * (2 * NFDIM) + c);
      float ek = efr[k];
      acc.x += ek * w.x; acc.y += ek * w.y; acc.z += ek * w.z; acc.w += ek * w.w;
    }
    uint2 pk;
    pk.x = (unsigned)f2bf(acc.x) | ((unsigned)f2bf(acc.y) << 16);
    pk.y = (unsigned)f2bf(acc.z) | ((unsigned)f2bf(acc.w) << 16);
    *(uint2*)(row + c) = pk;
  }
}

// ================= c2 message (line graph), angle RBF inline =================
__global__ __launch_bounds__(256) void k_angle_m2(
    const float* __restrict__ ef, const float* __restrict__ angle_h,
    const int* __restrict__ src, const int* __restrict__ dst,
    const float* __restrict__ Ws, const float* __restrict__ bs,
    const float* __restrict__ Wd, const float* __restrict__ bd,
    const float* __restrict__ We, const float* __restrict__ be,
    u16* __restrict__ m) {
  int a = blockIdx.x * blockDim.x + threadIdx.x;
  if (a >= N_ANGLESC) return;
  float xs[40], xd[40], xa[40];
  {
    const float4* p = (const float4*)(ef + (long long)src[a] * EFDIM);
    const float4* q = (const float4*)(ef + (long long)dst[a] * EFDIM);
#pragma unroll
    for (int i = 0; i < 10; i++) {
      float4 v = p[i]; xs[4 * i] = v.x; xs[4 * i + 1] = v.y; xs[4 * i + 2] = v.z; xs[4 * i + 3] = v.w;
      float4 u = q[i]; xd[4 * i] = u.x; xd[4 * i + 1] = u.y; xd[4 * i + 2] = u.z; xd[4 * i + 3] = u.w;
    }
    const float PI = 3.14159265358979323846f;
    const float step = PI / 39.f;
    const float g = 39.f / PI;
    float h = angle_h[a];
#pragma unroll
    for (int k = 0; k < 40; k++) {
      float d = h - (-PI * 0.5f + k * step);
      xa[k] = expf(-g * d * d);
    }
  }
  u16* row = m + (long long)a * (2 * EFDIM);
  for (int c4 = 0; c4 < 20; c4++) {
    int c = c4 * 4;
    float4 b1 = *(const float4*)(bs + c);
    float4 b2 = *(const float4*)(bd + c);
    float4 b3 = *(const float4*)(be + c);
    float4 acc;
    acc.x = b1.x + b2.x + b3.x; acc.y = b1.y + b2.y + b3.y;
    acc.z = b1.z + b2.z + b3.z; acc.w = b1.w + b2.w + b3.w;
#pragma unroll
    for (int k = 0; k < 40; k++) {
      float4 w1 = *(const float4*)(Ws + k * (2 * EFDIM) + c);
      float4 w2 = *(const float4*)(Wd + k * (2 * EFDIM) + c);
      float4 w3 = *(const float4*)(We + k * (2 * EFDIM) + c);
      float s = xs[k], d = xd[k], aa = xa[k];
      acc.x += s * w1.x + d * w2.x + aa * w3.x;
      acc.y += s * w1.y + d * w2.y + aa * w3.y;
      acc.z += s * w1.z + d * w2.z + aa * w3.z;
      acc.w += s * w1.w + d * w2.w + aa * w3.w;
    }
    uint2 pk;
    pk.x = (unsigned)f2bf(acc.x) | ((unsigned)f2bf(acc.y) << 16);
    pk.y = (unsigned)f2bf(acc.z) | ((unsigned)f2bf(acc.w) << 16);
    *(uint2*)(row + c) = pk;
  }
}

// ================= column stats, row-major bf16 [R][C] =================
__global__ void k_colstats_rmb(const u16* __restrict__ X, long long R, int C,
                               float* __restrict__ stat) {
  int c = threadIdx.x;
  if (c >= C) return;
  float s = 0.f, q = 0.f;
  for (long long rr = blockIdx.x; rr < R; rr += gridDim.x) {
    float v = bf2f(X[rr * C + c]);
    s += v; q += v * v;
  }
  atomicAdd(&stat[c], s);
  atomicAdd(&stat[C + c], q);
}

// ================= column stats, row-major fp32 [R][C] =================
__global__ void k_colstats_rm(const float* __restrict__ X, int R, int C,
                              float* __restrict__ stat) {
  int c = threadIdx.x;
  if (c >= C) return;
  float s = 0.f, q = 0.f;
  for (int rr = blockIdx.x; rr < R; rr += gridDim.x) {
    float v = X[(long long)rr * C + c];
    s += v; q += v * v;
  }
  atomicAdd(&stat[c], s);
  atomicAdd(&stat[C + c], q);
}

// ================= BN finalize =================
__global__ void k_finalize(const float* __restrict__ stat, const float* __restrict__ g,
                           const float* __restrict__ b, float* __restrict__ scsh,
                           int C, float invR) {
  int c = threadIdx.x + blockIdx.x * blockDim.x;
  if (c >= C) return;
  float mu = stat[c] * invR;
  float var = stat[C + c] * invR - mu * mu;
  float is = rsqrtf(var + 1e-5f);
  float sc = g[c] * is;
  scsh[c] = sc;
  scsh[C + c] = b[c] - mu * sc;
}

// ================= c1 aggregation: CSR gather, block per node =================
__global__ __launch_bounds__(128) void k_gather1(
    const u16* __restrict__ m, const int* __restrict__ perm, const int* __restrict__ offsets,
    const float* __restrict__ scsh, float* __restrict__ hagg) {
  int n = blockIdx.x;
  int c = threadIdx.x;
  if (c >= NFDIM) return;
  int lo = offsets[n], hi = offsets[n + 1];
  float sc_f = scsh[c],          sh_f = scsh[184 + c];
  float sc_s = scsh[92 + c],     sh_s = scsh[184 + 92 + c];
  float acc = 0.f;
  for (int p = lo; p < hi; ++p) {
    int e = perm[p];
    const u16* row = m + (long long)e * 184;
    float mf = bf2f(row[c]) * sc_f + sh_f;
    float ms = bf2f(row[92 + c]) * sc_s + sh_s;
    acc += sigmoidf_(mf) * softplusf_(ms);
  }
  hagg[(long long)n * NFDIM + c] = acc;
}

// ================= c2 aggregation: CSR gather, thread per (node, col) =================
__global__ __launch_bounds__(256) void k_gather2(
    const u16* __restrict__ m, const int* __restrict__ perm, const int* __restrict__ offsets,
    const float* __restrict__ scsh, u16* __restrict__ hagg) {
  long long idx = (long long)blockIdx.x * blockDim.x + threadIdx.x;
  if (idx >= (long long)N_EDGESC * EFDIM) return;
  int n = (int)(idx / EFDIM), c = (int)(idx - (long long)n * EFDIM);
  int lo = offsets[n], hi = offsets[n + 1];
  float sc_f = scsh[c],        sh_f = scsh[80 + c];
  float sc_s = scsh[40 + c],   sh_s = scsh[120 + c];
  float acc = 0.f;
  for (int p = lo; p < hi; ++p) {
    int e = perm[p];
    const u16* row = m + (long long)e * 80;
    float mf = bf2f(row[c]) * sc_f + sh_f;
    float ms = bf2f(row[40 + c]) * sc_s + sh_s;
    acc += sigmoidf_(mf) * softplusf_(ms);
  }
  hagg[idx] = f2bf(acc);
}

// ================= residual: out = softplus(xin + hagg*sc + sh) =================
__global__ void k_bn_residual(const float* __restrict__ xin, const float* __restrict__ hagg,
                              const float* __restrict__ scsh, float* __restrict__ out,
                              int total, int C) {
  int idx = blockIdx.x * blockDim.x + threadIdx.x;
  if (idx >= total) return;
  int c = idx % C;
  out[idx] = softplusf_(xin[idx] + hagg[idx] * scsh[c] + scsh[C + c]);
}

__global__ void k_bn_residual_b(const float* __restrict__ xin, const u16* __restrict__ hagg,
                                const float* __restrict__ scsh, float* __restrict__ out,
                                int total, int C) {
  int idx = blockIdx.x * blockDim.x + threadIdx.x;
  if (idx >= total) return;
  int c = idx % C;
  out[idx] = softplusf_(xin[idx] + bf2f(hagg[idx]) * scsh[c] + scsh[C + c]);
}

// ================= fused pool + head MLP: one block per graph =================
__global__ __launch_bounds__(256) void k_head(
    const float* __restrict__ nf, const int* __restrict__ gid,
    const float* __restrict__ fcW, const float* __restrict__ fcb,
    const float* __restrict__ outW, const float* __restrict__ outb,
    float* __restrict__ out) {
  __shared__ float feats[NFDIM];
  __shared__ float warpsum[4];
  int g = blockIdx.x, t = threadIdx.x;
  // lower_bound for g and g+1 in sorted gid
  int lo = 0, hi = N_NODES;
  while (lo < hi) { int mid = (lo + hi) >> 1; if (gid[mid] < g) lo = mid + 1; else hi = mid; }
  int lo2 = lo, hi2 = N_NODES;
  while (lo2 < hi2) { int mid = (lo2 + hi2) >> 1; if (gid[mid] < g + 1) lo2 = mid + 1; else hi2 = mid; }
  if (t < NFDIM) {
    float s = 0.f;
    for (int n = lo; n < lo2; ++n) s += nf[(long long)n * NFDIM + t];
    float cgt = fmaxf((float)(lo2 - lo), 1.f);
    feats[t] = softplusf_(s / cgt);
  }
  __syncthreads();
  float acc = fcb[t];
#pragma unroll 4
  for (int k = 0; k < NFDIM; k++) acc += feats[k] * fcW[k * FCDIM + t];
  float z = softplusf_(softplusf_(acc));
  float v = z * outW[t];
  for (int off = 32; off > 0; off >>= 1) v += __shfl_down(v, off, 64);
  if ((t & 63) == 0) warpsum[t >> 6] = v;
  __syncthreads();
  if (t == 0) out[g] = warpsum[0] + warpsum[1] + warpsum[2] + warpsum[3] + outb[0];
}

// ================= diagnostic sentinel =================
__global__ void k_sentinel(float* out, float v) {
  int i = blockIdx.x * blockDim.x + threadIdx.x;
  if (i < N_GRAPHSC) out[i] = v;
}

static inline int cdiv(long long a, long long b) { return (int)((a + b - 1) / b); }

extern "C" void kernel_launch(void* const* d_in, const int* in_sizes, int n_in,
                              void* d_out, int out_size, void* d_ws, size_t ws_size,
                              hipStream_t stream) {
  (void)in_sizes; (void)n_in; (void)out_size;
  const float* atom_features = (const float*)d_in[0];
  const float* r             = (const float*)d_in[1];
  const float* angle_h       = (const float*)d_in[2];
  const int*   g_src         = (const int*)d_in[3];
  const int*   g_dst         = (const int*)d_in[4];
  const int*   lg_src        = (const int*)d_in[5];
  const int*   lg_dst        = (const int*)d_in[6];
  const int*   node_gid      = (const int*)d_in[7];
  const float* emb_W         = (const float*)d_in[8];
  const float* emb_b         = (const float*)d_in[9];
  const float* c1_Wsrc       = (const float*)d_in[10];
  const float* c1_bsrc       = (const float*)d_in[11];
  const float* c1_Wdst       = (const float*)d_in[12];
  const float* c1_bdst       = (const float*)d_in[13];
  const float* c1_Wedge      = (const float*)d_in[14];
  const float* c1_bedge      = (const float*)d_in[15];
  const float* c1_bnm_g      = (const float*)d_in[16];
  const float* c1_bnm_b      = (const float*)d_in[17];
  const float* c1_bn_g       = (const float*)d_in[18];
  const float* c1_bn_b       = (const float*)d_in[19];
  const float* c2_Wsrc       = (const float*)d_in[20];
  const float* c2_bsrc       = (const float*)d_in[21];
  const float* c2_Wdst       = (const float*)d_in[22];
  const float* c2_bdst       = (const float*)d_in[23];
  const float* c2_Wedge      = (const float*)d_in[24];
  const float* c2_bedge      = (const float*)d_in[25];
  const float* c2_bnm_g      = (const float*)d_in[26];
  const float* c2_bnm_b      = (const float*)d_in[27];
  const float* c2_bn_g       = (const float*)d_in[28];
  const float* c2_bn_b       = (const float*)d_in[29];
  const float* fc_W          = (const float*)d_in[30];
  const float* fc_b          = (const float*)d_in[31];
  const float* out_W         = (const float*)d_in[32];
  const float* out_b         = (const float*)d_in[33];

  // ---- workspace layout ----
  char* basep = (char*)d_ws;
  size_t off = 0;
  auto walloc = [&](size_t bytes) {
    char* p = basep + off;
    off += (bytes + 255) & ~(size_t)255;
    return p;
  };
  u16*   M     = (u16*)walloc((size_t)58880000 * 2);   // message buffer [E][184] / [A][80] bf16
  float* EF    = (float*)walloc((size_t)12800000 * 4); // edge features (in-place)
  float* NF    = (float*)walloc((size_t)1840000 * 4);  // node features (in-place)
  float* HS1   = (float*)walloc((size_t)3680000 * 4);
  float* HD1   = (float*)walloc((size_t)3680000 * 4);
  float* HAGG1 = (float*)walloc((size_t)1840000 * 4);  // fp32 [N][92]
  u16*   HAGG2 = (u16*)walloc((size_t)12800000 * 2);   // bf16 [E][40]
  int*   HIST  = (int*)walloc((size_t)320000 * 4);     // shared histogram buffer
  int*   OFF1  = (int*)walloc((size_t)20001 * 4);
  int*   CUR1  = (int*)walloc((size_t)20000 * 4);
  int*   PERM1 = (int*)walloc((size_t)320000 * 4);
  int*   OFF2  = (int*)walloc((size_t)320001 * 4);
  int*   CUR2  = (int*)walloc((size_t)320000 * 4);
  int*   PERM2 = (int*)walloc((size_t)640000 * 4);
  int*   BSUM  = (int*)walloc((size_t)2048 * 4);
  float* STAT  = (float*)walloc(512 * 4);
  float* SCSHM = (float*)walloc(1024 * 4);
  float* SCSHN = (float*)walloc(512 * 4);
  if (ws_size < off) {
    k_sentinel<<<1, 256, 0, stream>>>((float*)d_out, (float)(ws_size >> 20));
    return;
  }

  // ---- CSR for atom graph (bins=N_NODES, E=N_EDGESC, dst=g_dst) ----
  {
    int NB = N_NODES, E = N_EDGESC;
    int B = cdiv(NB, 256);
    hipMemsetAsync(HIST, 0, (size_t)NB * 4, stream);
    k_hist<<<cdiv(E, 256), 256, 0, stream>>>(g_dst, E, HIST);
    k_scan_pass1<<<B, 256, 0, stream>>>(HIST, NB, BSUM);
    k_scan_partials<<<1, 256, 0, stream>>>(BSUM, B);
    k_scan_pass3<<<B, 256, 0, stream>>>(HIST, NB, E, BSUM, OFF1, CUR1);
    k_fill<<<cdiv(E, 256), 256, 0, stream>>>(g_dst, E, CUR1, PERM1);
    k_sortbins<<<cdiv(NB, 256), 256, 0, stream>>>(OFF1, PERM1, NB);
  }
  // ---- CSR for line graph (bins=N_EDGESC, E=N_ANGLESC, dst=lg_dst) ----
  {
    int NB = N_EDGESC, E = N_ANGLESC;
    int B = cdiv(NB, 256);
    hipMemsetAsync(HIST, 0, (size_t)NB * 4, stream);
    k_hist<<<cdiv(E, 256), 256, 0, stream>>>(lg_dst, E, HIST);
    k_scan_pass1<<<B, 256, 0, stream>>>(HIST, NB, BSUM);
    k_scan_partials<<<1, 256, 0, stream>>>(BSUM, B);
    k_scan_pass3<<<B, 256, 0, stream>>>(HIST, NB, E, BSUM, OFF2, CUR2);
    k_fill<<<cdiv(E, 256), 256, 0, stream>>>(lg_dst, E, CUR2, PERM2);
    k_sortbins<<<cdiv(NB, 256), 256, 0, stream>>>(OFF2, PERM2, NB);
  }

  // ---- features ----
  k_rbf_edge<<<cdiv(N_EDGESC, 256), 256, 0, stream>>>(r, EF);
  k_gemm_bias<<<cdiv((long long)N_NODES * NFDIM, 256), 256, 0, stream>>>(
      atom_features, emb_W, emb_b, NF, N_NODES, NFDIM, NFDIM);

  for (int i = 0; i < 3; i++) {
    // ---------- conv1 (atom graph) ----------
    k_gemm_bias<<<cdiv((long long)N_NODES * 2 * NFDIM, 256), 256, 0, stream>>>(
        NF, c1_Wsrc + i * NFDIM * 2 * NFDIM, c1_bsrc + i * 2 * NFDIM, HS1, N_NODES, 2 * NFDIM, NFDIM);
    k_gemm_bias<<<cdiv((long long)N_NODES * 2 * NFDIM, 256), 256, 0, stream>>>(
        NF, c1_Wdst + i * NFDIM * 2 * NFDIM, c1_bdst + i * 2 * NFDIM, HD1, N_NODES, 2 * NFDIM, NFDIM);
    k_edge_m1<<<cdiv(N_EDGESC, 256), 256, 0, stream>>>(
        HS1, HD1, EF, g_src, g_dst, c1_Wedge + i * EFDIM * 2 * NFDIM, c1_bedge + i * 2 * NFDIM, M);
    hipMemsetAsync(STAT, 0, 512 * sizeof(float), stream);
    k_colstats_rmb<<<2048, 192, 0, stream>>>(M, (long long)N_EDGESC, 184, STAT);
    k_finalize<<<1, 256, 0, stream>>>(STAT, c1_bnm_g + i * 184, c1_bnm_b + i * 184, SCSHM, 184, 1.f / N_EDGESC);
    k_gather1<<<N_NODES, 128, 0, stream>>>(M, PERM1, OFF1, SCSHM, HAGG1);
    hipMemsetAsync(STAT, 0, 512 * sizeof(float), stream);
    k_colstats_rm<<<512, 128, 0, stream>>>(HAGG1, N_NODES, 92, STAT);
    k_finalize<<<1, 256, 0, stream>>>(STAT, c1_bn_g + i * 92, c1_bn_b + i * 92, SCSHN, 92, 1.f / N_NODES);
    k_bn_residual<<<cdiv((long long)N_NODES * NFDIM, 256), 256, 0, stream>>>(
        NF, HAGG1, SCSHN, NF, N_NODES * NFDIM, NFDIM);

    // ---------- conv2 (line graph) ----------
    k_angle_m2<<<cdiv(N_ANGLESC, 256), 256, 0, stream>>>(
        EF, angle_h, lg_src, lg_dst,
        c2_Wsrc + i * EFDIM * 2 * EFDIM, c2_bsrc + i * 2 * EFDIM,
        c2_Wdst + i * EFDIM * 2 * EFDIM, c2_bdst + i * 2 * EFDIM,
        c2_Wedge + i * EFDIM * 2 * EFDIM, c2_bedge + i * 2 * EFDIM, M);
    hipMemsetAsync(STAT, 0, 512 * sizeof(float), stream);
    k_colstats_rmb<<<2048, 128, 0, stream>>>(M, (long long)N_ANGLESC, 80, STAT);
    k_finalize<<<1, 256, 0, stream>>>(STAT, c2_bnm_g + i * 80, c2_bnm_b + i * 80, SCSHM, 80, 1.f / N_ANGLESC);
    k_gather2<<<cdiv((long long)N_EDGESC * EFDIM, 256), 256, 0, stream>>>(M, PERM2, OFF2, SCSHM, HAGG2);
    hipMemsetAsync(STAT, 0, 512 * sizeof(float), stream);
    k_colstats_rmb<<<1024, 64, 0, stream>>>(HAGG2, (long long)N_EDGESC, 40, STAT);
    k_finalize<<<1, 256, 0, stream>>>(STAT, c2_bn_g + i * 40, c2_bn_b + i * 40, SCSHN, 40, 1.f / N_EDGESC);
    k_bn_residual_b<<<cdiv((long long)N_EDGESC * EFDIM, 256), 256, 0, stream>>>(
        EF, HAGG2, SCSHN, EF, N_EDGESC * EFDIM, EFDIM);
  }

  // ---------- readout (fused pool + head) ----------
  k_head<<<N_GRAPHSC, 256, 0, stream>>>(NF, node_gid, fc_W, fc_b, out_W, out_b, (float*)d_out);
}

// Round 4
// 5192.382 us; speedup vs baseline: 2.2877x; 1.0162x over previous
//
#include <hip/hip_runtime.h>
#include <math.h>

#define N_NODES   20000
#define N_EDGESC  320000
#define N_ANGLESC 640000
#define N_GRAPHSC 256
#define NFDIM     92
#define EFDIM     40
#define FCDIM     256

typedef unsigned short u16;

__device__ __forceinline__ float softplusf_(float x) {
  return fmaxf(x, 0.f) + log1pf(expf(-fabsf(x)));
}
__device__ __forceinline__ float sigmoidf_(float x) {
  return 1.f / (1.f + expf(-x));
}
__device__ __forceinline__ u16 f2bf(float x) {
  union { float f; unsigned u; } v; v.f = x;
  unsigned r = v.u + 0x7fff + ((v.u >> 16) & 1);
  return (u16)(r >> 16);
}
__device__ __forceinline__ float bf2f(u16 h) {
  union { unsigned u; float f; } v; v.u = ((unsigned)h) << 16; return v.f;
}
__device__ __forceinline__ unsigned pk2(float a, float b) {
  return (unsigned)f2bf(a) | ((unsigned)f2bf(b) << 16);
}

// ================= CSR construction (deterministic) =================
__global__ void k_hist(const int* __restrict__ dst, int E, int* __restrict__ hist) {
  int e = blockIdx.x * blockDim.x + threadIdx.x;
  if (e < E) atomicAdd(&hist[dst[e]], 1);
}

__global__ void k_scan_pass1(const int* __restrict__ hist, int n, int* __restrict__ bsum) {
  __shared__ int buf[256];
  int i = blockIdx.x * 256 + threadIdx.x;
  buf[threadIdx.x] = (i < n) ? hist[i] : 0;
  __syncthreads();
  for (int o = 128; o > 0; o >>= 1) {
    if (threadIdx.x < o) buf[threadIdx.x] += buf[threadIdx.x + o];
    __syncthreads();
  }
  if (threadIdx.x == 0) bsum[blockIdx.x] = buf[0];
}

__global__ void k_scan_partials(int* __restrict__ bsum, int B) {
  __shared__ int buf[256];
  __shared__ int carry;
  if (threadIdx.x == 0) carry = 0;
  __syncthreads();
  for (int base = 0; base < B; base += 256) {
    int i = base + threadIdx.x;
    int v = (i < B) ? bsum[i] : 0;
    buf[threadIdx.x] = v;
    __syncthreads();
    for (int o = 1; o < 256; o <<= 1) {
      int t = (threadIdx.x >= o) ? buf[threadIdx.x - o] : 0;
      __syncthreads();
      buf[threadIdx.x] += t;
      __syncthreads();
    }
    if (i < B) bsum[i] = buf[threadIdx.x] - v + carry;
    int tile_total = buf[255];
    __syncthreads();
    if (threadIdx.x == 0) carry += tile_total;
    __syncthreads();
  }
}

__global__ void k_scan_pass3(const int* __restrict__ hist, int n, int total,
                             const int* __restrict__ bsum,
                             int* __restrict__ offsets, int* __restrict__ cursor) {
  __shared__ int buf[256];
  int i = blockIdx.x * 256 + threadIdx.x;
  int v = (i < n) ? hist[i] : 0;
  buf[threadIdx.x] = v;
  __syncthreads();
  for (int o = 1; o < 256; o <<= 1) {
    int t = (threadIdx.x >= o) ? buf[threadIdx.x - o] : 0;
    __syncthreads();
    buf[threadIdx.x] += t;
    __syncthreads();
  }
  int excl = buf[threadIdx.x] - v + bsum[blockIdx.x];
  if (i < n) {
    offsets[i] = excl;
    cursor[i] = excl;
    if (i == n - 1) offsets[n] = total;
  }
}

__global__ void k_fill(const int* __restrict__ dst, int E,
                       int* __restrict__ cursor, int* __restrict__ perm) {
  int e = blockIdx.x * blockDim.x + threadIdx.x;
  if (e >= E) return;
  int pos = atomicAdd(&cursor[dst[e]], 1);
  perm[pos] = e;
}

__global__ void k_sortbins(const int* __restrict__ offsets, int* __restrict__ perm, int nb) {
  int n = blockIdx.x * blockDim.x + threadIdx.x;
  if (n >= nb) return;
  int lo = offsets[n], hi = offsets[n + 1];
  for (int i = lo + 1; i < hi; i++) {
    int key = perm[i];
    int j = i - 1;
    while (j >= lo && perm[j] > key) { perm[j + 1] = perm[j]; j--; }
    perm[j + 1] = key;
  }
}

// ================= features: fused bondlen + RBF, bf16 out =================
__global__ void k_rbf_edge(const float* __restrict__ r, u16* __restrict__ ef) {
  int e = blockIdx.x * blockDim.x + threadIdx.x;
  if (e >= N_EDGESC) return;
  float x = r[e * 3 + 0], y = r[e * 3 + 1], z = r[e * 3 + 2];
  float bl = sqrtf(x * x + y * y + z * z);
  const float step = 8.f / 39.f;
  const float g = 39.f / 8.f;
  unsigned* o = (unsigned*)(ef + (long long)e * EFDIM);
#pragma unroll
  for (int i = 0; i < 20; i++) {
    float d0 = bl - (2 * i + 0) * step;
    float d1 = bl - (2 * i + 1) * step;
    o[i] = pk2(expf(-g * d0 * d0), expf(-g * d1 * d1));
  }
}

// ================= naive small GEMM (embedding only) =================
__global__ void k_gemm_bias(const float* __restrict__ A, const float* __restrict__ W,
                            const float* __restrict__ b, float* __restrict__ C,
                            int M, int N, int K) {
  int idx = blockIdx.x * blockDim.x + threadIdx.x;
  int total = M * N;
  if (idx >= total) return;
  int row = idx / N, col = idx - row * N;
  const float* a = A + (long long)row * K;
  float acc = b[col];
#pragma unroll 4
  for (int k = 0; k < K; k++) acc += a[k] * W[k * N + col];
  C[idx] = acc;
}

// ================= tiled GEMM: HS/HD = NF @ W + b  (fp32 out) =================
// A [20000][92] fp32, W [92][184] fp32, OUT [20000][184] fp32
__global__ __launch_bounds__(256) void k_nf_gemm(
    const float* __restrict__ A, const float* __restrict__ W,
    const float* __restrict__ bias, float* __restrict__ OUT) {
  __shared__ float As[64][93];
  __shared__ float Wls[92][64];
  __shared__ float bls[64];
  int t = threadIdx.x;
  int row0 = blockIdx.x * 64;
  int ct = blockIdx.y * 64;
  int cvalid = 184 - ct; if (cvalid > 64) cvalid = 64;
  for (int idx = t; idx < 64 * 92; idx += 256) {
    int rr = idx / 92, k = idx - rr * 92;
    int rg = row0 + rr;
    As[rr][k] = (rg < N_NODES) ? A[(long long)rg * 92 + k] : 0.f;
  }
  for (int idx = t; idx < 92 * 64; idx += 256) {
    int k = idx >> 6, c = idx & 63;
    Wls[k][c] = (c < cvalid) ? W[k * 184 + ct + c] : 0.f;
  }
  if (t < 64) bls[t] = (t < cvalid) ? bias[ct + t] : 0.f;
  __syncthreads();
  int rg = t >> 4, cg = t & 15;
  int r0 = rg * 4, c0 = cg * 4;
  float acc[4][4] = {};
#pragma unroll 2
  for (int k = 0; k < 92; k++) {
    float a0 = As[r0][k], a1 = As[r0 + 1][k], a2 = As[r0 + 2][k], a3 = As[r0 + 3][k];
    float4 w = *(float4*)&Wls[k][c0];
    acc[0][0] += a0 * w.x; acc[0][1] += a0 * w.y; acc[0][2] += a0 * w.z; acc[0][3] += a0 * w.w;
    acc[1][0] += a1 * w.x; acc[1][1] += a1 * w.y; acc[1][2] += a1 * w.z; acc[1][3] += a1 * w.w;
    acc[2][0] += a2 * w.x; acc[2][1] += a2 * w.y; acc[2][2] += a2 * w.z; acc[2][3] += a2 * w.w;
    acc[3][0] += a3 * w.x; acc[3][1] += a3 * w.y; acc[3][2] += a3 * w.z; acc[3][3] += a3 * w.w;
  }
  if (c0 < cvalid) {
    float b0 = bls[c0], b1 = bls[c0 + 1], b2 = bls[c0 + 2], b3 = bls[c0 + 3];
#pragma unroll
    for (int i = 0; i < 4; i++) {
      int rg2 = row0 + r0 + i;
      if (rg2 < N_NODES) {
        float4 o;
        o.x = acc[i][0] + b0; o.y = acc[i][1] + b1;
        o.z = acc[i][2] + b2; o.w = acc[i][3] + b3;
        *(float4*)&OUT[(long long)rg2 * 184 + ct + c0] = o;
      }
    }
  }
}

// ================= conv1 message: M[e][c] = bf16(EF@We + be + HS[src] + HD[dst]) =================
__global__ __launch_bounds__(256) void k_conv1_msg(
    const u16* __restrict__ EF, const int* __restrict__ src, const int* __restrict__ dst,
    const float* __restrict__ HS, const float* __restrict__ HD,
    const float* __restrict__ We, const float* __restrict__ be, u16* __restrict__ M) {
  __shared__ u16 As[64][41];
  __shared__ float Wls[40][64];
  __shared__ float bls[64];
  __shared__ int srcs[64], dsts[64];
  int t = threadIdx.x;
  int e0 = blockIdx.x * 64;
  int ct = blockIdx.y * 64;
  int cvalid = 184 - ct; if (cvalid > 64) cvalid = 64;
  if (t < 64) {
    srcs[t] = src[e0 + t];
    dsts[t] = dst[e0 + t];
    bls[t] = (t < cvalid) ? be[ct + t] : 0.f;
  }
  for (int idx = t; idx < 64 * 40; idx += 256) {
    int rr = idx / 40, k = idx - rr * 40;
    As[rr][k] = EF[(long long)(e0 + rr) * 40 + k];
  }
  for (int idx = t; idx < 40 * 64; idx += 256) {
    int k = idx >> 6, c = idx & 63;
    Wls[k][c] = (c < cvalid) ? We[k * 184 + ct + c] : 0.f;
  }
  __syncthreads();
  int rg = t >> 4, cg = t & 15;
  int r0 = rg * 4, c0 = cg * 4;
  float acc[4][4] = {};
#pragma unroll 4
  for (int k = 0; k < 40; k++) {
    float a0 = bf2f(As[r0][k]), a1 = bf2f(As[r0 + 1][k]);
    float a2 = bf2f(As[r0 + 2][k]), a3 = bf2f(As[r0 + 3][k]);
    float4 w = *(float4*)&Wls[k][c0];
    acc[0][0] += a0 * w.x; acc[0][1] += a0 * w.y; acc[0][2] += a0 * w.z; acc[0][3] += a0 * w.w;
    acc[1][0] += a1 * w.x; acc[1][1] += a1 * w.y; acc[1][2] += a1 * w.z; acc[1][3] += a1 * w.w;
    acc[2][0] += a2 * w.x; acc[2][1] += a2 * w.y; acc[2][2] += a2 * w.z; acc[2][3] += a2 * w.w;
    acc[3][0] += a3 * w.x; acc[3][1] += a3 * w.y; acc[3][2] += a3 * w.z; acc[3][3] += a3 * w.w;
  }
  if (c0 < cvalid) {
    float b0 = bls[c0], b1 = bls[c0 + 1], b2 = bls[c0 + 2], b3 = bls[c0 + 3];
#pragma unroll
    for (int i = 0; i < 4; i++) {
      int e = e0 + r0 + i;
      const float4 hs = *(const float4*)&HS[(long long)srcs[r0 + i] * 184 + ct + c0];
      const float4 hd = *(const float4*)&HD[(long long)dsts[r0 + i] * 184 + ct + c0];
      float v0 = acc[i][0] + b0 + hs.x + hd.x;
      float v1 = acc[i][1] + b1 + hs.y + hd.y;
      float v2 = acc[i][2] + b2 + hs.z + hd.z;
      float v3 = acc[i][3] + b3 + hs.w + hd.w;
      uint2 pkd; pkd.x = pk2(v0, v1); pkd.y = pk2(v2, v3);
      *(uint2*)(M + (long long)e * 184 + ct + c0) = pkd;
    }
  }
}

// ================= conv2 message: M[a][c] = bf16([EFsrc|EFdst|RBF(h)] @ [Ws|Wd|We] + bsum) =================
__global__ __launch_bounds__(320) void k_conv2_msg(
    const u16* __restrict__ EF, const float* __restrict__ angle_h,
    const int* __restrict__ lsrc, const int* __restrict__ ldst,
    const float* __restrict__ Ws, const float* __restrict__ bs,
    const float* __restrict__ Wd, const float* __restrict__ bd,
    const float* __restrict__ We, const float* __restrict__ be,
    u16* __restrict__ M) {
  __shared__ u16 As[64][121];
  __shared__ float Wls[120][80];
  __shared__ float bls[80];
  __shared__ int srcl[64], dstl[64];
  __shared__ float hh[64];
  int t = threadIdx.x;
  int a0 = blockIdx.x * 64;
  if (t < 64) {
    srcl[t] = lsrc[a0 + t];
    dstl[t] = ldst[a0 + t];
    hh[t] = angle_h[a0 + t];
  } else if (t < 144) {
    int c = t - 64;
    bls[c] = bs[c] + bd[c] + be[c];
  }
  __syncthreads();
  for (int idx = t; idx < 64 * 40; idx += 320) {
    int rr = idx / 40, k = idx - rr * 40;
    As[rr][k] = EF[(long long)srcl[rr] * 40 + k];
  }
  for (int idx = t; idx < 64 * 40; idx += 320) {
    int rr = idx / 40, k = idx - rr * 40;
    As[rr][40 + k] = EF[(long long)dstl[rr] * 40 + k];
  }
  {
    const float PI = 3.14159265358979323846f;
    const float step = PI / 39.f;
    const float g = 39.f / PI;
    for (int idx = t; idx < 64 * 40; idx += 320) {
      int rr = idx / 40, k = idx - rr * 40;
      float d = hh[rr] - (-PI * 0.5f + k * step);
      As[rr][80 + k] = f2bf(expf(-g * d * d));
    }
  }
  for (int idx = t; idx < 120 * 80; idx += 320) {
    int k = idx / 80, c = idx - k * 80;
    float w = (k < 40) ? Ws[k * 80 + c] : ((k < 80) ? Wd[(k - 40) * 80 + c] : We[(k - 80) * 80 + c]);
    Wls[k][c] = w;
  }
  __syncthreads();
  int rg = t / 20, cg = t - rg * 20;
  int r0 = rg * 4, c0 = cg * 4;
  float acc[4][4] = {};
#pragma unroll 2
  for (int k = 0; k < 120; k++) {
    float a0v = bf2f(As[r0][k]), a1 = bf2f(As[r0 + 1][k]);
    float a2 = bf2f(As[r0 + 2][k]), a3 = bf2f(As[r0 + 3][k]);
    float4 w = *(float4*)&Wls[k][c0];
    acc[0][0] += a0v * w.x; acc[0][1] += a0v * w.y; acc[0][2] += a0v * w.z; acc[0][3] += a0v * w.w;
    acc[1][0] += a1 * w.x; acc[1][1] += a1 * w.y; acc[1][2] += a1 * w.z; acc[1][3] += a1 * w.w;
    acc[2][0] += a2 * w.x; acc[2][1] += a2 * w.y; acc[2][2] += a2 * w.z; acc[2][3] += a2 * w.w;
    acc[3][0] += a3 * w.x; acc[3][1] += a3 * w.y; acc[3][2] += a3 * w.z; acc[3][3] += a3 * w.w;
  }
  float b0 = bls[c0], b1 = bls[c0 + 1], b2 = bls[c0 + 2], b3 = bls[c0 + 3];
#pragma unroll
  for (int i = 0; i < 4; i++) {
    int a = a0 + r0 + i;
    uint2 pkd;
    pkd.x = pk2(acc[i][0] + b0, acc[i][1] + b1);
    pkd.y = pk2(acc[i][2] + b2, acc[i][3] + b3);
    *(uint2*)(M + (long long)a * 80 + c0) = pkd;
  }
}

// ================= column stats, row-major bf16 [R][C] =================
__global__ void k_colstats_rmb(const u16* __restrict__ X, long long R, int C,
                               float* __restrict__ stat) {
  int c = threadIdx.x;
  if (c >= C) return;
  float s = 0.f, q = 0.f;
  for (long long rr = blockIdx.x; rr < R; rr += gridDim.x) {
    float v = bf2f(X[rr * C + c]);
    s += v; q += v * v;
  }
  atomicAdd(&stat[c], s);
  atomicAdd(&stat[C + c], q);
}

// ================= column stats, row-major fp32 [R][C] =================
__global__ void k_colstats_rm(const float* __restrict__ X, int R, int C,
                              float* __restrict__ stat) {
  int c = threadIdx.x;
  if (c >= C) return;
  float s = 0.f, q = 0.f;
  for (int rr = blockIdx.x; rr < R; rr += gridDim.x) {
    float v = X[(long long)rr * C + c];
    s += v; q += v * v;
  }
  atomicAdd(&stat[c], s);
  atomicAdd(&stat[C + c], q);
}

// ================= BN finalize =================
__global__ void k_finalize(const float* __restrict__ stat, const float* __restrict__ g,
                           const float* __restrict__ b, float* __restrict__ scsh,
                           int C, float invR) {
  int c = threadIdx.x + blockIdx.x * blockDim.x;
  if (c >= C) return;
  float mu = stat[c] * invR;
  float var = stat[C + c] * invR - mu * mu;
  float is = rsqrtf(var + 1e-5f);
  float sc = g[c] * is;
  scsh[c] = sc;
  scsh[C + c] = b[c] - mu * sc;
}

// ================= c1 aggregation: CSR gather, block per node =================
__global__ __launch_bounds__(128) void k_gather1(
    const u16* __restrict__ m, const int* __restrict__ perm, const int* __restrict__ offsets,
    const float* __restrict__ scsh, float* __restrict__ hagg) {
  int n = blockIdx.x;
  int c = threadIdx.x;
  if (c >= NFDIM) return;
  int lo = offsets[n], hi = offsets[n + 1];
  float sc_f = scsh[c],          sh_f = scsh[184 + c];
  float sc_s = scsh[92 + c],     sh_s = scsh[184 + 92 + c];
  float acc = 0.f;
  for (int p = lo; p < hi; ++p) {
    int e = perm[p];
    const u16* row = m + (long long)e * 184;
    float mf = bf2f(row[c]) * sc_f + sh_f;
    float ms = bf2f(row[92 + c]) * sc_s + sh_s;
    acc += sigmoidf_(mf) * softplusf_(ms);
  }
  hagg[(long long)n * NFDIM + c] = acc;
}

// ================= c2 aggregation: CSR gather, thread per (edge, col) =================
__global__ __launch_bounds__(256) void k_gather2(
    const u16* __restrict__ m, const int* __restrict__ perm, const int* __restrict__ offsets,
    const float* __restrict__ scsh, u16* __restrict__ hagg) {
  long long idx = (long long)blockIdx.x * blockDim.x + threadIdx.x;
  if (idx >= (long long)N_EDGESC * EFDIM) return;
  int n = (int)(idx / EFDIM), c = (int)(idx - (long long)n * EFDIM);
  int lo = offsets[n], hi = offsets[n + 1];
  float sc_f = scsh[c],        sh_f = scsh[80 + c];
  float sc_s = scsh[40 + c],   sh_s = scsh[120 + c];
  float acc = 0.f;
  for (int p = lo; p < hi; ++p) {
    int e = perm[p];
    const u16* row = m + (long long)e * 80;
    float mf = bf2f(row[c]) * sc_f + sh_f;
    float ms = bf2f(row[40 + c]) * sc_s + sh_s;
    acc += sigmoidf_(mf) * softplusf_(ms);
  }
  hagg[idx] = f2bf(acc);
}

// ================= residuals =================
__global__ void k_bn_residual(const float* __restrict__ xin, const float* __restrict__ hagg,
                              const float* __restrict__ scsh, float* __restrict__ out,
                              int total, int C) {
  int idx = blockIdx.x * blockDim.x + threadIdx.x;
  if (idx >= total) return;
  int c = idx % C;
  out[idx] = softplusf_(xin[idx] + hagg[idx] * scsh[c] + scsh[C + c]);
}

__global__ void k_bn_residual_bb(u16* __restrict__ ef, const u16* __restrict__ hagg,
                                 const float* __restrict__ scsh, int total, int C) {
  int idx = blockIdx.x * blockDim.x + threadIdx.x;
  if (idx >= total) return;
  int c = idx % C;
  float v = softplusf_(bf2f(ef[idx]) + bf2f(hagg[idx]) * scsh[c] + scsh[C + c]);
  ef[idx] = f2bf(v);
}

// ================= fused pool + head MLP: one block per graph =================
__global__ __launch_bounds__(256) void k_head(
    const float* __restrict__ nf, const int* __restrict__ gid,
    const float* __restrict__ fcW, const float* __restrict__ fcb,
    const float* __restrict__ outW, const float* __restrict__ outb,
    float* __restrict__ out) {
  __shared__ float feats[NFDIM];
  __shared__ float warpsum[4];
  int g = blockIdx.x, t = threadIdx.x;
  int lo = 0, hi = N_NODES;
  while (lo < hi) { int mid = (lo + hi) >> 1; if (gid[mid] < g) lo = mid + 1; else hi = mid; }
  int lo2 = lo, hi2 = N_NODES;
  while (lo2 < hi2) { int mid = (lo2 + hi2) >> 1; if (gid[mid] < g + 1) lo2 = mid + 1; else hi2 = mid; }
  if (t < NFDIM) {
    float s = 0.f;
    for (int n = lo; n < lo2; ++n) s += nf[(long long)n * NFDIM + t];
    float cgt = fmaxf((float)(lo2 - lo), 1.f);
    feats[t] = softplusf_(s / cgt);
  }
  __syncthreads();
  float acc = fcb[t];
#pragma unroll 4
  for (int k = 0; k < NFDIM; k++) acc += feats[k] * fcW[k * FCDIM + t];
  float z = softplusf_(softplusf_(acc));
  float v = z * outW[t];
  for (int off = 32; off > 0; off >>= 1) v += __shfl_down(v, off, 64);
  if ((t & 63) == 0) warpsum[t >> 6] = v;
  __syncthreads();
  if (t == 0) out[g] = warpsum[0] + warpsum[1] + warpsum[2] + warpsum[3] + outb[0];
}

// ================= diagnostic sentinel =================
__global__ void k_sentinel(float* out, float v) {
  int i = blockIdx.x * blockDim.x + threadIdx.x;
  if (i < N_GRAPHSC) out[i] = v;
}

static inline int cdiv(long long a, long long b) { return (int)((a + b - 1) / b); }

extern "C" void kernel_launch(void* const* d_in, const int* in_sizes, int n_in,
                              void* d_out, int out_size, void* d_ws, size_t ws_size,
                              hipStream_t stream) {
  (void)in_sizes; (void)n_in; (void)out_size;
  const float* atom_features = (const float*)d_in[0];
  const float* r             = (const float*)d_in[1];
  const float* angle_h       = (const float*)d_in[2];
  const int*   g_src         = (const int*)d_in[3];
  const int*   g_dst         = (const int*)d_in[4];
  const int*   lg_src        = (const int*)d_in[5];
  const int*   lg_dst        = (const int*)d_in[6];
  const int*   node_gid      = (const int*)d_in[7];
  const float* emb_W         = (const float*)d_in[8];
  const float* emb_b         = (const float*)d_in[9];
  const float* c1_Wsrc       = (const float*)d_in[10];
  const float* c1_bsrc       = (const float*)d_in[11];
  const float* c1_Wdst       = (const float*)d_in[12];
  const float* c1_bdst       = (const float*)d_in[13];
  const float* c1_Wedge      = (const float*)d_in[14];
  const float* c1_bedge      = (const float*)d_in[15];
  const float* c1_bnm_g      = (const float*)d_in[16];
  const float* c1_bnm_b      = (const float*)d_in[17];
  const float* c1_bn_g       = (const float*)d_in[18];
  const float* c1_bn_b       = (const float*)d_in[19];
  const float* c2_Wsrc       = (const float*)d_in[20];
  const float* c2_bsrc       = (const float*)d_in[21];
  const float* c2_Wdst       = (const float*)d_in[22];
  const float* c2_bdst       = (const float*)d_in[23];
  const float* c2_Wedge      = (const float*)d_in[24];
  const float* c2_bedge      = (const float*)d_in[25];
  const float* c2_bnm_g      = (const float*)d_in[26];
  const float* c2_bnm_b      = (const float*)d_in[27];
  const float* c2_bn_g       = (const float*)d_in[28];
  const float* c2_bn_b       = (const float*)d_in[29];
  const float* fc_W          = (const float*)d_in[30];
  const float* fc_b          = (const float*)d_in[31];
  const float* out_W         = (const float*)d_in[32];
  const float* out_b         = (const float*)d_in[33];

  // ---- workspace layout (~221 MB) ----
  char* basep = (char*)d_ws;
  size_t off = 0;
  auto walloc = [&](size_t bytes) {
    char* p = basep + off;
    off += (bytes + 255) & ~(size_t)255;
    return p;
  };
  u16*   M     = (u16*)walloc((size_t)58880000 * 2);   // msg buffer [320k][184] / [640k][80] bf16
  u16*   EF    = (u16*)walloc((size_t)12800000 * 2);   // edge features bf16 (in-place)
  float* NF    = (float*)walloc((size_t)1840000 * 4);  // node features fp32 (in-place)
  float* HS1   = (float*)walloc((size_t)3680000 * 4);  // h_src table fp32
  float* HD1   = (float*)walloc((size_t)3680000 * 4);  // h_dst table fp32
  float* HAGG1 = (float*)walloc((size_t)1840000 * 4);  // fp32 [N][92]
  u16*   HAGG2 = (u16*)walloc((size_t)12800000 * 2);   // bf16 [E][40]
  int*   HIST  = (int*)walloc((size_t)320000 * 4);
  int*   OFF1  = (int*)walloc((size_t)20001 * 4);
  int*   CUR1  = (int*)walloc((size_t)20000 * 4);
  int*   PERM1 = (int*)walloc((size_t)320000 * 4);
  int*   OFF2  = (int*)walloc((size_t)320001 * 4);
  int*   CUR2  = (int*)walloc((size_t)320000 * 4);
  int*   PERM2 = (int*)walloc((size_t)640000 * 4);
  int*   BSUM  = (int*)walloc((size_t)2048 * 4);
  float* STAT  = (float*)walloc(512 * 4);
  float* SCSHM = (float*)walloc(1024 * 4);
  float* SCSHN = (float*)walloc(512 * 4);
  if (ws_size < off) {
    k_sentinel<<<1, 256, 0, stream>>>((float*)d_out, (float)(ws_size >> 20));
    return;
  }

  // ---- CSR for atom graph ----
  {
    int NB = N_NODES, E = N_EDGESC;
    int B = cdiv(NB, 256);
    hipMemsetAsync(HIST, 0, (size_t)NB * 4, stream);
    k_hist<<<cdiv(E, 256), 256, 0, stream>>>(g_dst, E, HIST);
    k_scan_pass1<<<B, 256, 0, stream>>>(HIST, NB, BSUM);
    k_scan_partials<<<1, 256, 0, stream>>>(BSUM, B);
    k_scan_pass3<<<B, 256, 0, stream>>>(HIST, NB, E, BSUM, OFF1, CUR1);
    k_fill<<<cdiv(E, 256), 256, 0, stream>>>(g_dst, E, CUR1, PERM1);
    k_sortbins<<<cdiv(NB, 256), 256, 0, stream>>>(OFF1, PERM1, NB);
  }
  // ---- CSR for line graph ----
  {
    int NB = N_EDGESC, E = N_ANGLESC;
    int B = cdiv(NB, 256);
    hipMemsetAsync(HIST, 0, (size_t)NB * 4, stream);
    k_hist<<<cdiv(E, 256), 256, 0, stream>>>(lg_dst, E, HIST);
    k_scan_pass1<<<B, 256, 0, stream>>>(HIST, NB, BSUM);
    k_scan_partials<<<1, 256, 0, stream>>>(BSUM, B);
    k_scan_pass3<<<B, 256, 0, stream>>>(HIST, NB, E, BSUM, OFF2, CUR2);
    k_fill<<<cdiv(E, 256), 256, 0, stream>>>(lg_dst, E, CUR2, PERM2);
    k_sortbins<<<cdiv(NB, 256), 256, 0, stream>>>(OFF2, PERM2, NB);
  }

  // ---- features ----
  k_rbf_edge<<<cdiv(N_EDGESC, 256), 256, 0, stream>>>(r, EF);
  k_gemm_bias<<<cdiv((long long)N_NODES * NFDIM, 256), 256, 0, stream>>>(
      atom_features, emb_W, emb_b, NF, N_NODES, NFDIM, NFDIM);

  dim3 gNF(cdiv(N_NODES, 64), 3);
  dim3 gC1(N_EDGESC / 64, 3);
  dim3 gC2(N_ANGLESC / 64, 1);

  for (int i = 0; i < 3; i++) {
    // ---------- conv1 (atom graph) ----------
    k_nf_gemm<<<gNF, 256, 0, stream>>>(NF, c1_Wsrc + i * NFDIM * 2 * NFDIM, c1_bsrc + i * 2 * NFDIM, HS1);
    k_nf_gemm<<<gNF, 256, 0, stream>>>(NF, c1_Wdst + i * NFDIM * 2 * NFDIM, c1_bdst + i * 2 * NFDIM, HD1);
    k_conv1_msg<<<gC1, 256, 0, stream>>>(
        EF, g_src, g_dst, HS1, HD1, c1_Wedge + i * EFDIM * 2 * NFDIM, c1_bedge + i * 2 * NFDIM, M);
    hipMemsetAsync(STAT, 0, 512 * sizeof(float), stream);
    k_colstats_rmb<<<2048, 192, 0, stream>>>(M, (long long)N_EDGESC, 184, STAT);
    k_finalize<<<1, 256, 0, stream>>>(STAT, c1_bnm_g + i * 184, c1_bnm_b + i * 184, SCSHM, 184, 1.f / N_EDGESC);
    k_gather1<<<N_NODES, 128, 0, stream>>>(M, PERM1, OFF1, SCSHM, HAGG1);
    hipMemsetAsync(STAT, 0, 512 * sizeof(float), stream);
    k_colstats_rm<<<512, 128, 0, stream>>>(HAGG1, N_NODES, 92, STAT);
    k_finalize<<<1, 256, 0, stream>>>(STAT, c1_bn_g + i * 92, c1_bn_b + i * 92, SCSHN, 92, 1.f / N_NODES);
    k_bn_residual<<<cdiv((long long)N_NODES * NFDIM, 256), 256, 0, stream>>>(
        NF, HAGG1, SCSHN, NF, N_NODES * NFDIM, NFDIM);

    // ---------- conv2 (line graph) ----------
    k_conv2_msg<<<gC2, 320, 0, stream>>>(
        EF, angle_h, lg_src, lg_dst,
        c2_Wsrc + i * EFDIM * 2 * EFDIM, c2_bsrc + i * 2 * EFDIM,
        c2_Wdst + i * EFDIM * 2 * EFDIM, c2_bdst + i * 2 * EFDIM,
        c2_Wedge + i * EFDIM * 2 * EFDIM, c2_bedge + i * 2 * EFDIM, M);
    hipMemsetAsync(STAT, 0, 512 * sizeof(float), stream);
    k_colstats_rmb<<<2048, 128, 0, stream>>>(M, (long long)N_ANGLESC, 80, STAT);
    k_finalize<<<1, 256, 0, stream>>>(STAT, c2_bnm_g + i * 80, c2_bnm_b + i * 80, SCSHM, 80, 1.f / N_ANGLESC);
    k_gather2<<<cdiv((long long)N_EDGESC * EFDIM, 256), 256, 0, stream>>>(M, PERM2, OFF2, SCSHM, HAGG2);
    hipMemsetAsync(STAT, 0, 512 * sizeof(float), stream);
    k_colstats_rmb<<<1024, 64, 0, stream>>>(HAGG2, (long long)N_EDGESC, 40, STAT);
    k_finalize<<<1, 256, 0, stream>>>(STAT, c2_bn_g + i * 40, c2_bn_b + i * 40, SCSHN, 40, 1.f / N_EDGESC);
    k_bn_residual_bb<<<cdiv((long long)N_EDGESC * EFDIM, 256), 256, 0, stream>>>(
        EF, HAGG2, SCSHN, N_EDGESC * EFDIM, EFDIM);
  }

  // ---------- readout ----------
  k_head<<<N_GRAPHSC, 256, 0, stream>>>(NF, node_gid, fc_W, fc_b, out_W, out_b, (float*)d_out);
}

// Round 5
// 2987.852 us; speedup vs baseline: 3.9756x; 1.7378x over previous
//
#include <hip/hip_runtime.h>
#include <math.h>

#define N_NODES   20000
#define N_EDGESC  320000
#define N_ANGLESC 640000
#define N_GRAPHSC 256
#define NFDIM     92
#define EFDIM     40
#define FCDIM     256

typedef unsigned short u16;
typedef unsigned int u32;
typedef __attribute__((ext_vector_type(8))) short bf16x8;
typedef __attribute__((ext_vector_type(4))) float f32x4;

__device__ __forceinline__ float softplusf_(float x) {
  return fmaxf(x, 0.f) + log1pf(expf(-fabsf(x)));
}
__device__ __forceinline__ float sigmoidf_(float x) {
  return 1.f / (1.f + expf(-x));
}
__device__ __forceinline__ u16 f2bf(float x) {
  union { float f; unsigned u; } v; v.f = x;
  unsigned r = v.u + 0x7fff + ((v.u >> 16) & 1);
  return (u16)(r >> 16);
}
__device__ __forceinline__ float bf2f(u16 h) {
  union { unsigned u; float f; } v; v.u = ((unsigned)h) << 16; return v.f;
}
__device__ __forceinline__ u32 pk2(float a, float b) {
  return (u32)f2bf(a) | ((u32)f2bf(b) << 16);
}

// ================= CSR construction (deterministic) =================
__global__ void k_hist(const int* __restrict__ dst, int E, int* __restrict__ hist) {
  int e = blockIdx.x * blockDim.x + threadIdx.x;
  if (e < E) atomicAdd(&hist[dst[e]], 1);
}

__global__ void k_scan_pass1(const int* __restrict__ hist, int n, int* __restrict__ bsum) {
  __shared__ int buf[256];
  int i = blockIdx.x * 256 + threadIdx.x;
  buf[threadIdx.x] = (i < n) ? hist[i] : 0;
  __syncthreads();
  for (int o = 128; o > 0; o >>= 1) {
    if (threadIdx.x < o) buf[threadIdx.x] += buf[threadIdx.x + o];
    __syncthreads();
  }
  if (threadIdx.x == 0) bsum[blockIdx.x] = buf[0];
}

__global__ void k_scan_partials(int* __restrict__ bsum, int B) {
  __shared__ int buf[256];
  __shared__ int carry;
  if (threadIdx.x == 0) carry = 0;
  __syncthreads();
  for (int base = 0; base < B; base += 256) {
    int i = base + threadIdx.x;
    int v = (i < B) ? bsum[i] : 0;
    buf[threadIdx.x] = v;
    __syncthreads();
    for (int o = 1; o < 256; o <<= 1) {
      int t = (threadIdx.x >= o) ? buf[threadIdx.x - o] : 0;
      __syncthreads();
      buf[threadIdx.x] += t;
      __syncthreads();
    }
    if (i < B) bsum[i] = buf[threadIdx.x] - v + carry;
    int tile_total = buf[255];
    __syncthreads();
    if (threadIdx.x == 0) carry += tile_total;
    __syncthreads();
  }
}

__global__ void k_scan_pass3(const int* __restrict__ hist, int n, int total,
                             const int* __restrict__ bsum,
                             int* __restrict__ offsets, int* __restrict__ cursor) {
  __shared__ int buf[256];
  int i = blockIdx.x * 256 + threadIdx.x;
  int v = (i < n) ? hist[i] : 0;
  buf[threadIdx.x] = v;
  __syncthreads();
  for (int o = 1; o < 256; o <<= 1) {
    int t = (threadIdx.x >= o) ? buf[threadIdx.x - o] : 0;
    __syncthreads();
    buf[threadIdx.x] += t;
    __syncthreads();
  }
  int excl = buf[threadIdx.x] - v + bsum[blockIdx.x];
  if (i < n) {
    offsets[i] = excl;
    cursor[i] = excl;
    if (i == n - 1) offsets[n] = total;
  }
}

__global__ void k_fill(const int* __restrict__ dst, int E,
                       int* __restrict__ cursor, int* __restrict__ perm) {
  int e = blockIdx.x * blockDim.x + threadIdx.x;
  if (e >= E) return;
  int pos = atomicAdd(&cursor[dst[e]], 1);
  perm[pos] = e;
}

__global__ void k_sortbins(const int* __restrict__ offsets, int* __restrict__ perm, int nb) {
  int n = blockIdx.x * blockDim.x + threadIdx.x;
  if (n >= nb) return;
  int lo = offsets[n], hi = offsets[n + 1];
  for (int i = lo + 1; i < hi; i++) {
    int key = perm[i];
    int j = i - 1;
    while (j >= lo && perm[j] > key) { perm[j + 1] = perm[j]; j--; }
    perm[j + 1] = key;
  }
}

// ================= features: fused bondlen + RBF, bf16 out =================
__global__ void k_rbf_edge(const float* __restrict__ r, u16* __restrict__ ef) {
  int e = blockIdx.x * blockDim.x + threadIdx.x;
  if (e >= N_EDGESC) return;
  float x = r[e * 3 + 0], y = r[e * 3 + 1], z = r[e * 3 + 2];
  float bl = sqrtf(x * x + y * y + z * z);
  const float step = 8.f / 39.f;
  const float g = 39.f / 8.f;
  u32* o = (u32*)(ef + (long long)e * EFDIM);
#pragma unroll
  for (int i = 0; i < 20; i++) {
    float d0 = bl - (2 * i + 0) * step;
    float d1 = bl - (2 * i + 1) * step;
    o[i] = pk2(expf(-g * d0 * d0), expf(-g * d1 * d1));
  }
}

// ================= naive small GEMM (embedding only) =================
__global__ void k_gemm_bias(const float* __restrict__ A, const float* __restrict__ W,
                            const float* __restrict__ b, float* __restrict__ C,
                            int M, int N, int K) {
  int idx = blockIdx.x * blockDim.x + threadIdx.x;
  int total = M * N;
  if (idx >= total) return;
  int row = idx / N, col = idx - row * N;
  const float* a = A + (long long)row * K;
  float acc = b[col];
#pragma unroll 4
  for (int k = 0; k < K; k++) acc += a[k] * W[k * N + col];
  C[idx] = acc;
}

// ================= tiled GEMM: HS/HD = NF @ W + b (fp32 out) =================
__global__ __launch_bounds__(256) void k_nf_gemm(
    const float* __restrict__ A, const float* __restrict__ W,
    const float* __restrict__ bias, float* __restrict__ OUT) {
  __shared__ float As[64][93];
  __shared__ float Wls[92][64];
  __shared__ float bls[64];
  int t = threadIdx.x;
  int row0 = blockIdx.x * 64;
  int ct = blockIdx.y * 64;
  int cvalid = 184 - ct; if (cvalid > 64) cvalid = 64;
  for (int idx = t; idx < 64 * 92; idx += 256) {
    int rr = idx / 92, k = idx - rr * 92;
    int rg = row0 + rr;
    As[rr][k] = (rg < N_NODES) ? A[(long long)rg * 92 + k] : 0.f;
  }
  for (int idx = t; idx < 92 * 64; idx += 256) {
    int k = idx >> 6, c = idx & 63;
    Wls[k][c] = (c < cvalid) ? W[k * 184 + ct + c] : 0.f;
  }
  if (t < 64) bls[t] = (t < cvalid) ? bias[ct + t] : 0.f;
  __syncthreads();
  int rg = t >> 4, cg = t & 15;
  int r0 = rg * 4, c0 = cg * 4;
  float acc[4][4] = {};
#pragma unroll 2
  for (int k = 0; k < 92; k++) {
    float a0 = As[r0][k], a1 = As[r0 + 1][k], a2 = As[r0 + 2][k], a3 = As[r0 + 3][k];
    float4 w = *(float4*)&Wls[k][c0];
    acc[0][0] += a0 * w.x; acc[0][1] += a0 * w.y; acc[0][2] += a0 * w.z; acc[0][3] += a0 * w.w;
    acc[1][0] += a1 * w.x; acc[1][1] += a1 * w.y; acc[1][2] += a1 * w.z; acc[1][3] += a1 * w.w;
    acc[2][0] += a2 * w.x; acc[2][1] += a2 * w.y; acc[2][2] += a2 * w.z; acc[2][3] += a2 * w.w;
    acc[3][0] += a3 * w.x; acc[3][1] += a3 * w.y; acc[3][2] += a3 * w.z; acc[3][3] += a3 * w.w;
  }
  if (c0 < cvalid) {
    float b0 = bls[c0], b1 = bls[c0 + 1], b2 = bls[c0 + 2], b3 = bls[c0 + 3];
#pragma unroll
    for (int i = 0; i < 4; i++) {
      int rg2 = row0 + r0 + i;
      if (rg2 < N_NODES) {
        float4 o;
        o.x = acc[i][0] + b0; o.y = acc[i][1] + b1;
        o.z = acc[i][2] + b2; o.w = acc[i][3] + b3;
        *(float4*)&OUT[(long long)rg2 * 184 + ct + c0] = o;
      }
    }
  }
}

// ================= weight transpose+swizzle kernels (per layer) =================
// WT1: [192 rows=c][64 k] bf16, 128B rows, chunk^(c&7) swizzle; k=40 row = bias, rest pad 0
__global__ void k_mkwt1(const float* __restrict__ We, const float* __restrict__ be,
                        u16* __restrict__ WT1) {
  int idx = blockIdx.x * blockDim.x + threadIdx.x;
  if (idx >= 192 * 64) return;
  int c = idx >> 6, k = idx & 63;
  float v = 0.f;
  if (c < 184) {
    if (k < 40) v = We[k * 184 + c];
    else if (k == 40) v = be[c];
  }
  int b = 2 * k;
  int off = c * 128 + (((b >> 4) ^ (c & 7)) << 4) + (b & 15);
  WT1[off >> 1] = f2bf(v);
}

// WT2: [80 rows=c][128 k] bf16, 256B rows, chunk^(c&7) swizzle; k=120 = summed bias
__global__ void k_mkwt2(const float* __restrict__ Ws, const float* __restrict__ bs,
                        const float* __restrict__ Wd, const float* __restrict__ bd,
                        const float* __restrict__ We, const float* __restrict__ be,
                        u16* __restrict__ WT2) {
  int idx = blockIdx.x * blockDim.x + threadIdx.x;
  if (idx >= 80 * 128) return;
  int c = idx >> 7, k = idx & 127;
  float v = 0.f;
  if (k < 40) v = Ws[k * 80 + c];
  else if (k < 80) v = Wd[(k - 40) * 80 + c];
  else if (k < 120) v = We[(k - 80) * 80 + c];
  else if (k == 120) v = bs[c] + bd[c] + be[c];
  int b = 2 * k;
  int off = c * 256 + (((b >> 4) ^ (c & 7)) << 4) + (b & 15);
  WT2[off >> 1] = f2bf(v);
}

// ================= conv1 message via MFMA =================
// M[e][c] = bf16( EF[e]@We + be + HS[src[e]][c] + HD[dst[e]][c] ), fused col stats -> PART
__global__ __launch_bounds__(256) void k_conv1_mfma(
    const u16* __restrict__ EF, const int* __restrict__ src, const int* __restrict__ dst,
    const float* __restrict__ HS, const float* __restrict__ HD,
    const u16* __restrict__ WT1, u16* __restrict__ M, float* __restrict__ PART) {
  __shared__ __align__(16) char sA[64 * 128];   // [64 rows][64 k] bf16, swizzled
  __shared__ __align__(16) char sB[192 * 128];  // [192 c][64 k] bf16, swizzled
  __shared__ float ssum[2][192];
  __shared__ int srcs[64], dsts[64];
  int t = threadIdx.x;
  int e0 = blockIdx.x * 64;
  for (int i = t; i < 2 * 192; i += 256) ((float*)ssum)[i] = 0.f;
  if (t < 64) {
    srcs[t] = src[e0 + t];
    dsts[t] = dst[e0 + t];
    // bias + pad chunks 5..7 of row t
    uint4 z5 = {0x00003F80u, 0u, 0u, 0u};  // k=40 -> 1.0 bf16
    uint4 z = {0u, 0u, 0u, 0u};
    *(uint4*)(sA + t * 128 + ((5 ^ (t & 7)) << 4)) = z5;
    *(uint4*)(sA + t * 128 + ((6 ^ (t & 7)) << 4)) = z;
    *(uint4*)(sA + t * 128 + ((7 ^ (t & 7)) << 4)) = z;
  }
  {  // A: 64 rows x 5 uint4 of EF (rows are consecutive edges)
    const uint4* efg = (const uint4*)EF;
    for (int i = t; i < 320; i += 256) {
      int r = i / 5, ch = i % 5;
      uint4 v = efg[(long long)(e0 + r) * 5 + ch];
      *(uint4*)(sA + r * 128 + ((ch ^ (r & 7)) << 4)) = v;
    }
  }
  {  // B: flat copy of pre-swizzled WT1 (24576 B)
    const uint4* wg = (const uint4*)WT1;
    uint4* bb = (uint4*)sB;
    for (int i = t; i < 1536; i += 256) bb[i] = wg[i];
  }
  __syncthreads();

  int lane = t & 63, w = t >> 6;
  int lr = lane & 15, lg = lane >> 4;
  int arow = w * 16 + lr;
  f32x4 zero = {0.f, 0.f, 0.f, 0.f};
  f32x4 acc[12];
#pragma unroll
  for (int n = 0; n < 12; n++) acc[n] = zero;
#pragma unroll
  for (int kt = 0; kt < 2; kt++) {
    bf16x8 a = *(const bf16x8*)(sA + arow * 128 + (((kt * 4 + lg) ^ (arow & 7)) << 4));
#pragma unroll
    for (int n = 0; n < 12; n++) {
      int brow = n * 16 + lr;
      bf16x8 b = *(const bf16x8*)(sB + brow * 128 + (((kt * 4 + lg) ^ (brow & 7)) << 4));
      acc[n] = __builtin_amdgcn_mfma_f32_16x16x32_bf16(a, b, acc[n], 0, 0, 0);
    }
  }
  int base_r = w * 16 + lg * 4;
#pragma unroll
  for (int n = 0; n < 12; n++) {
    int col = n * 16 + lr;
    bool valid = col < 184;
    float s = 0.f, q = 0.f;
#pragma unroll
    for (int j = 0; j < 4; j++) {
      int r = base_r + j;
      float v = acc[n][j];
      if (valid) {
        v += HS[(long long)srcs[r] * 184 + col] + HD[(long long)dsts[r] * 184 + col];
        M[(long long)(e0 + r) * 184 + col] = f2bf(v);
        s += v; q += v * v;
      }
    }
    s += __shfl_xor(s, 16, 64); s += __shfl_xor(s, 32, 64);
    q += __shfl_xor(q, 16, 64); q += __shfl_xor(q, 32, 64);
    if (valid && lg == 0) {
      atomicAdd(&ssum[0][col], s);
      atomicAdd(&ssum[1][col], q);
    }
  }
  __syncthreads();
  float* P = PART + (long long)blockIdx.x * 368;
  for (int i = t; i < 184; i += 256) { P[i] = ssum[0][i]; P[184 + i] = ssum[1][i]; }
}

// ================= conv2 message via MFMA =================
// M[a][c] = bf16( [EFsrc|EFdst|RBF(h)|1] @ [Ws;Wd;We;bias] ), fused col stats -> PART
__global__ __launch_bounds__(256) void k_conv2_mfma(
    const u16* __restrict__ EF, const float* __restrict__ angle_h,
    const int* __restrict__ lsrc, const int* __restrict__ ldst,
    const u16* __restrict__ WT2, u16* __restrict__ M, float* __restrict__ PART) {
  __shared__ __align__(16) char sA[64 * 256];  // [64 rows][128 k] bf16, swizzled
  __shared__ __align__(16) char sB[80 * 256];  // [80 c][128 k] bf16, swizzled
  __shared__ float ssum[2][80];
  __shared__ int srcl[64], dstl[64];
  __shared__ float hh[64];
  int t = threadIdx.x;
  int a0 = blockIdx.x * 64;
  if (t < 64) { srcl[t] = lsrc[a0 + t]; dstl[t] = ldst[a0 + t]; hh[t] = angle_h[a0 + t]; }
  for (int i = t; i < 160; i += 256) ((float*)ssum)[i] = 0.f;
  __syncthreads();
  int lane = t & 63, w = t >> 6;
  if (w == 0) {          // EF[src] -> k 0..39
    int r = lane;
    const uint4* g = (const uint4*)EF + (long long)srcl[r] * 5;
#pragma unroll
    for (int ch = 0; ch < 5; ch++)
      *(uint4*)(sA + r * 256 + ((ch ^ (r & 7)) << 4)) = g[ch];
  } else if (w == 1) {   // EF[dst] -> k 40..79
    int r = lane;
    const uint4* g = (const uint4*)EF + (long long)dstl[r] * 5;
#pragma unroll
    for (int ch = 0; ch < 5; ch++)
      *(uint4*)(sA + r * 256 + (((ch + 5) ^ (r & 7)) << 4)) = g[ch];
  } else {               // RBF -> k 80..119, bias/pad chunk 15
    int r = lane;
    const float PI = 3.14159265358979323846f;
    const float step = PI / 39.f;
    const float gam = 39.f / PI;
    float h = hh[r];
    int k0 = (w == 2) ? 0 : 20;
#pragma unroll
    for (int p = 0; p < 10; p++) {
      int k = k0 + 2 * p;
      float d0 = h - (-PI * 0.5f + k * step);
      float d1 = h - (-PI * 0.5f + (k + 1) * step);
      u32 val = pk2(expf(-gam * d0 * d0), expf(-gam * d1 * d1));
      int b = 160 + 2 * k;
      *(u32*)(sA + r * 256 + (((b >> 4) ^ (r & 7)) << 4) + (b & 15)) = val;
    }
    if (w == 3) {
      uint4 z15 = {0x00003F80u, 0u, 0u, 0u};  // k=120 -> 1.0
      *(uint4*)(sA + r * 256 + ((15 ^ (r & 7)) << 4)) = z15;
    }
  }
  {  // B: flat copy of pre-swizzled WT2 (20480 B)
    const uint4* wg = (const uint4*)WT2;
    uint4* bb = (uint4*)sB;
    for (int i = t; i < 1280; i += 256) bb[i] = wg[i];
  }
  __syncthreads();

  int lr = lane & 15, lg = lane >> 4;
  int arow = w * 16 + lr;
  f32x4 zero = {0.f, 0.f, 0.f, 0.f};
  f32x4 acc[5];
#pragma unroll
  for (int n = 0; n < 5; n++) acc[n] = zero;
#pragma unroll
  for (int kt = 0; kt < 4; kt++) {
    bf16x8 a = *(const bf16x8*)(sA + arow * 256 + (((kt * 4 + lg) ^ (arow & 7)) << 4));
#pragma unroll
    for (int n = 0; n < 5; n++) {
      int brow = n * 16 + lr;
      bf16x8 b = *(const bf16x8*)(sB + brow * 256 + (((kt * 4 + lg) ^ (brow & 7)) << 4));
      acc[n] = __builtin_amdgcn_mfma_f32_16x16x32_bf16(a, b, acc[n], 0, 0, 0);
    }
  }
  int base_r = w * 16 + lg * 4;
#pragma unroll
  for (int n = 0; n < 5; n++) {
    int col = n * 16 + lr;
    float s = 0.f, q = 0.f;
#pragma unroll
    for (int j = 0; j < 4; j++) {
      float v = acc[n][j];
      M[(long long)(a0 + base_r + j) * 80 + col] = f2bf(v);
      s += v; q += v * v;
    }
    s += __shfl_xor(s, 16, 64); s += __shfl_xor(s, 32, 64);
    q += __shfl_xor(q, 16, 64); q += __shfl_xor(q, 32, 64);
    if (lg == 0) {
      atomicAdd(&ssum[0][col], s);
      atomicAdd(&ssum[1][col], q);
    }
  }
  __syncthreads();
  float* P = PART + (long long)blockIdx.x * 160;
  for (int i = t; i < 80; i += 256) { P[i] = ssum[0][i]; P[80 + i] = ssum[1][i]; }
}

// ================= PART reduction -> STAT =================
__global__ void k_reduce_part(const float* __restrict__ part, int nblk, int C2,
                              float* __restrict__ stat) {
  int c = blockIdx.x * blockDim.x + threadIdx.x;
  if (c >= C2) return;
  int chunks = gridDim.y;
  int per = (nblk + chunks - 1) / chunks;
  int lo = blockIdx.y * per;
  int hi = lo + per; if (hi > nblk) hi = nblk;
  float s = 0.f;
  for (int b = lo; b < hi; b++) s += part[(long long)b * C2 + c];
  atomicAdd(&stat[c], s);
}

// ================= column stats (fp32 / bf16 row-major) =================
__global__ void k_colstats_rm(const float* __restrict__ X, int R, int C,
                              float* __restrict__ stat) {
  int c = threadIdx.x;
  if (c >= C) return;
  float s = 0.f, q = 0.f;
  for (int rr = blockIdx.x; rr < R; rr += gridDim.x) {
    float v = X[(long long)rr * C + c];
    s += v; q += v * v;
  }
  atomicAdd(&stat[c], s);
  atomicAdd(&stat[C + c], q);
}

__global__ void k_colstats_rmb(const u16* __restrict__ X, long long R, int C,
                               float* __restrict__ stat) {
  int c = threadIdx.x;
  if (c >= C) return;
  float s = 0.f, q = 0.f;
  for (long long rr = blockIdx.x; rr < R; rr += gridDim.x) {
    float v = bf2f(X[rr * C + c]);
    s += v; q += v * v;
  }
  atomicAdd(&stat[c], s);
  atomicAdd(&stat[C + c], q);
}

// ================= BN finalize =================
__global__ void k_finalize(const float* __restrict__ stat, const float* __restrict__ g,
                           const float* __restrict__ b, float* __restrict__ scsh,
                           int C, float invR) {
  int c = threadIdx.x + blockIdx.x * blockDim.x;
  if (c >= C) return;
  float mu = stat[c] * invR;
  float var = stat[C + c] * invR - mu * mu;
  float is = rsqrtf(var + 1e-5f);
  float sc = g[c] * is;
  scsh[c] = sc;
  scsh[C + c] = b[c] - mu * sc;
}

// ================= c1 aggregation: CSR gather, block per node =================
__global__ __launch_bounds__(128) void k_gather1(
    const u16* __restrict__ m, const int* __restrict__ perm, const int* __restrict__ offsets,
    const float* __restrict__ scsh, float* __restrict__ hagg) {
  int n = blockIdx.x;
  int c = threadIdx.x;
  if (c >= NFDIM) return;
  int lo = offsets[n], hi = offsets[n + 1];
  float sc_f = scsh[c],       sh_f = scsh[184 + c];
  float sc_s = scsh[92 + c],  sh_s = scsh[184 + 92 + c];
  float acc = 0.f;
  for (int p = lo; p < hi; ++p) {
    int e = perm[p];
    const u16* row = m + (long long)e * 184;
    float mf = bf2f(row[c]) * sc_f + sh_f;
    float ms = bf2f(row[92 + c]) * sc_s + sh_s;
    acc += sigmoidf_(mf) * softplusf_(ms);
  }
  hagg[(long long)n * NFDIM + c] = acc;
}

// ================= c2 aggregation: CSR gather, thread per (edge, col) =================
__global__ __launch_bounds__(256) void k_gather2(
    const u16* __restrict__ m, const int* __restrict__ perm, const int* __restrict__ offsets,
    const float* __restrict__ scsh, u16* __restrict__ hagg) {
  long long idx = (long long)blockIdx.x * blockDim.x + threadIdx.x;
  if (idx >= (long long)N_EDGESC * EFDIM) return;
  int n = (int)(idx / EFDIM), c = (int)(idx - (long long)n * EFDIM);
  int lo = offsets[n], hi = offsets[n + 1];
  float sc_f = scsh[c],      sh_f = scsh[80 + c];
  float sc_s = scsh[40 + c], sh_s = scsh[120 + c];
  float acc = 0.f;
  for (int p = lo; p < hi; ++p) {
    int e = perm[p];
    const u16* row = m + (long long)e * 80;
    float mf = bf2f(row[c]) * sc_f + sh_f;
    float ms = bf2f(row[40 + c]) * sc_s + sh_s;
    acc += sigmoidf_(mf) * softplusf_(ms);
  }
  hagg[idx] = f2bf(acc);
}

// ================= residuals =================
__global__ void k_bn_residual(const float* __restrict__ xin, const float* __restrict__ hagg,
                              const float* __restrict__ scsh, float* __restrict__ out,
                              int total, int C) {
  int idx = blockIdx.x * blockDim.x + threadIdx.x;
  if (idx >= total) return;
  int c = idx % C;
  out[idx] = softplusf_(xin[idx] + hagg[idx] * scsh[c] + scsh[C + c]);
}

__global__ void k_bn_residual_bb(u16* __restrict__ ef, const u16* __restrict__ hagg,
                                 const float* __restrict__ scsh, int total, int C) {
  int idx = blockIdx.x * blockDim.x + threadIdx.x;
  if (idx >= total) return;
  int c = idx % C;
  float v = softplusf_(bf2f(ef[idx]) + bf2f(hagg[idx]) * scsh[c] + scsh[C + c]);
  ef[idx] = f2bf(v);
}

// ================= fused pool + head MLP: one block per graph =================
__global__ __launch_bounds__(256) void k_head(
    const float* __restrict__ nf, const int* __restrict__ gid,
    const float* __restrict__ fcW, const float* __restrict__ fcb,
    const float* __restrict__ outW, const float* __restrict__ outb,
    float* __restrict__ out) {
  __shared__ float feats[NFDIM];
  __shared__ float warpsum[4];
  int g = blockIdx.x, t = threadIdx.x;
  int lo = 0, hi = N_NODES;
  while (lo < hi) { int mid = (lo + hi) >> 1; if (gid[mid] < g) lo = mid + 1; else hi = mid; }
  int lo2 = lo, hi2 = N_NODES;
  while (lo2 < hi2) { int mid = (lo2 + hi2) >> 1; if (gid[mid] < g + 1) lo2 = mid + 1; else hi2 = mid; }
  if (t < NFDIM) {
    float s = 0.f;
    for (int n = lo; n < lo2; ++n) s += nf[(long long)n * NFDIM + t];
    float cgt = fmaxf((float)(lo2 - lo), 1.f);
    feats[t] = softplusf_(s / cgt);
  }
  __syncthreads();
  float acc = fcb[t];
#pragma unroll 4
  for (int k = 0; k < NFDIM; k++) acc += feats[k] * fcW[k * FCDIM + t];
  float z = softplusf_(softplusf_(acc));
  float v = z * outW[t];
  for (int off = 32; off > 0; off >>= 1) v += __shfl_down(v, off, 64);
  if ((t & 63) == 0) warpsum[t >> 6] = v;
  __syncthreads();
  if (t == 0) out[g] = warpsum[0] + warpsum[1] + warpsum[2] + warpsum[3] + outb[0];
}

// ================= diagnostic sentinel =================
__global__ void k_sentinel(float* out, float v) {
  int i = blockIdx.x * blockDim.x + threadIdx.x;
  if (i < N_GRAPHSC) out[i] = v;
}

static inline int cdiv(long long a, long long b) { return (int)((a + b - 1) / b); }

extern "C" void kernel_launch(void* const* d_in, const int* in_sizes, int n_in,
                              void* d_out, int out_size, void* d_ws, size_t ws_size,
                              hipStream_t stream) {
  (void)in_sizes; (void)n_in; (void)out_size;
  const float* atom_features = (const float*)d_in[0];
  const float* r             = (const float*)d_in[1];
  const float* angle_h       = (const float*)d_in[2];
  const int*   g_src         = (const int*)d_in[3];
  const int*   g_dst         = (const int*)d_in[4];
  const int*   lg_src        = (const int*)d_in[5];
  const int*   lg_dst        = (const int*)d_in[6];
  const int*   node_gid      = (const int*)d_in[7];
  const float* emb_W         = (const float*)d_in[8];
  const float* emb_b         = (const float*)d_in[9];
  const float* c1_Wsrc       = (const float*)d_in[10];
  const float* c1_bsrc       = (const float*)d_in[11];
  const float* c1_Wdst       = (const float*)d_in[12];
  const float* c1_bdst       = (const float*)d_in[13];
  const float* c1_Wedge      = (const float*)d_in[14];
  const float* c1_bedge      = (const float*)d_in[15];
  const float* c1_bnm_g      = (const float*)d_in[16];
  const float* c1_bnm_b      = (const float*)d_in[17];
  const float* c1_bn_g       = (const float*)d_in[18];
  const float* c1_bn_b       = (const float*)d_in[19];
  const float* c2_Wsrc       = (const float*)d_in[20];
  const float* c2_bsrc       = (const float*)d_in[21];
  const float* c2_Wdst       = (const float*)d_in[22];
  const float* c2_bdst       = (const float*)d_in[23];
  const float* c2_Wedge      = (const float*)d_in[24];
  const float* c2_bedge      = (const float*)d_in[25];
  const float* c2_bnm_g      = (const float*)d_in[26];
  const float* c2_bnm_b      = (const float*)d_in[27];
  const float* c2_bn_g       = (const float*)d_in[28];
  const float* c2_bn_b       = (const float*)d_in[29];
  const float* fc_W          = (const float*)d_in[30];
  const float* fc_b          = (const float*)d_in[31];
  const float* out_W         = (const float*)d_in[32];
  const float* out_b         = (const float*)d_in[33];

  // ---- workspace layout (~229 MB) ----
  char* basep = (char*)d_ws;
  size_t off = 0;
  auto walloc = [&](size_t bytes) {
    char* p = basep + off;
    off += (bytes + 255) & ~(size_t)255;
    return p;
  };
  u16*   M     = (u16*)walloc((size_t)58880000 * 2);
  u16*   EF    = (u16*)walloc((size_t)12800000 * 2);
  float* NF    = (float*)walloc((size_t)1840000 * 4);
  float* HS1   = (float*)walloc((size_t)3680000 * 4);
  float* HD1   = (float*)walloc((size_t)3680000 * 4);
  float* HAGG1 = (float*)walloc((size_t)1840000 * 4);
  u16*   HAGG2 = (u16*)walloc((size_t)12800000 * 2);
  float* PART  = (float*)walloc((size_t)5000 * 368 * 4);  // also fits 10000*160
  int*   HIST  = (int*)walloc((size_t)320000 * 4);
  int*   OFF1  = (int*)walloc((size_t)20001 * 4);
  int*   CUR1  = (int*)walloc((size_t)20000 * 4);
  int*   PERM1 = (int*)walloc((size_t)320000 * 4);
  int*   OFF2  = (int*)walloc((size_t)320001 * 4);
  int*   CUR2  = (int*)walloc((size_t)320000 * 4);
  int*   PERM2 = (int*)walloc((size_t)640000 * 4);
  int*   BSUM  = (int*)walloc((size_t)2048 * 4);
  u16*   WT1   = (u16*)walloc((size_t)192 * 64 * 2);
  u16*   WT2   = (u16*)walloc((size_t)80 * 128 * 2);
  float* STAT  = (float*)walloc(512 * 4);
  float* SCSHM = (float*)walloc(1024 * 4);
  float* SCSHN = (float*)walloc(512 * 4);
  if (ws_size < off) {
    k_sentinel<<<1, 256, 0, stream>>>((float*)d_out, (float)(ws_size >> 20));
    return;
  }

  // ---- CSR for atom graph ----
  {
    int NB = N_NODES, E = N_EDGESC;
    int B = cdiv(NB, 256);
    hipMemsetAsync(HIST, 0, (size_t)NB * 4, stream);
    k_hist<<<cdiv(E, 256), 256, 0, stream>>>(g_dst, E, HIST);
    k_scan_pass1<<<B, 256, 0, stream>>>(HIST, NB, BSUM);
    k_scan_partials<<<1, 256, 0, stream>>>(BSUM, B);
    k_scan_pass3<<<B, 256, 0, stream>>>(HIST, NB, E, BSUM, OFF1, CUR1);
    k_fill<<<cdiv(E, 256), 256, 0, stream>>>(g_dst, E, CUR1, PERM1);
    k_sortbins<<<cdiv(NB, 256), 256, 0, stream>>>(OFF1, PERM1, NB);
  }
  // ---- CSR for line graph ----
  {
    int NB = N_EDGESC, E = N_ANGLESC;
    int B = cdiv(NB, 256);
    hipMemsetAsync(HIST, 0, (size_t)NB * 4, stream);
    k_hist<<<cdiv(E, 256), 256, 0, stream>>>(lg_dst, E, HIST);
    k_scan_pass1<<<B, 256, 0, stream>>>(HIST, NB, BSUM);
    k_scan_partials<<<1, 256, 0, stream>>>(BSUM, B);
    k_scan_pass3<<<B, 256, 0, stream>>>(HIST, NB, E, BSUM, OFF2, CUR2);
    k_fill<<<cdiv(E, 256), 256, 0, stream>>>(lg_dst, E, CUR2, PERM2);
    k_sortbins<<<cdiv(NB, 256), 256, 0, stream>>>(OFF2, PERM2, NB);
  }

  // ---- features ----
  k_rbf_edge<<<cdiv(N_EDGESC, 256), 256, 0, stream>>>(r, EF);
  k_gemm_bias<<<cdiv((long long)N_NODES * NFDIM, 256), 256, 0, stream>>>(
      atom_features, emb_W, emb_b, NF, N_NODES, NFDIM, NFDIM);

  dim3 gNF(cdiv(N_NODES, 64), 3);

  for (int i = 0; i < 3; i++) {
    // ---------- conv1 (atom graph) ----------
    k_mkwt1<<<48, 256, 0, stream>>>(c1_Wedge + i * EFDIM * 2 * NFDIM, c1_bedge + i * 2 * NFDIM, WT1);
    k_nf_gemm<<<gNF, 256, 0, stream>>>(NF, c1_Wsrc + i * NFDIM * 2 * NFDIM, c1_bsrc + i * 2 * NFDIM, HS1);
    k_nf_gemm<<<gNF, 256, 0, stream>>>(NF, c1_Wdst + i * NFDIM * 2 * NFDIM, c1_bdst + i * 2 * NFDIM, HD1);
    k_conv1_mfma<<<N_EDGESC / 64, 256, 0, stream>>>(EF, g_src, g_dst, HS1, HD1, WT1, M, PART);
    hipMemsetAsync(STAT, 0, 512 * sizeof(float), stream);
    k_reduce_part<<<dim3(2, 32), 256, 0, stream>>>(PART, N_EDGESC / 64, 368, STAT);
    k_finalize<<<1, 256, 0, stream>>>(STAT, c1_bnm_g + i * 184, c1_bnm_b + i * 184, SCSHM, 184, 1.f / N_EDGESC);
    k_gather1<<<N_NODES, 128, 0, stream>>>(M, PERM1, OFF1, SCSHM, HAGG1);
    hipMemsetAsync(STAT, 0, 512 * sizeof(float), stream);
    k_colstats_rm<<<512, 128, 0, stream>>>(HAGG1, N_NODES, 92, STAT);
    k_finalize<<<1, 256, 0, stream>>>(STAT, c1_bn_g + i * 92, c1_bn_b + i * 92, SCSHN, 92, 1.f / N_NODES);
    k_bn_residual<<<cdiv((long long)N_NODES * NFDIM, 256), 256, 0, stream>>>(
        NF, HAGG1, SCSHN, NF, N_NODES * NFDIM, NFDIM);

    // ---------- conv2 (line graph) ----------
    k_mkwt2<<<40, 256, 0, stream>>>(
        c2_Wsrc + i * EFDIM * 2 * EFDIM, c2_bsrc + i * 2 * EFDIM,
        c2_Wdst + i * EFDIM * 2 * EFDIM, c2_bdst + i * 2 * EFDIM,
        c2_Wedge + i * EFDIM * 2 * EFDIM, c2_bedge + i * 2 * EFDIM, WT2);
    k_conv2_mfma<<<N_ANGLESC / 64, 256, 0, stream>>>(EF, angle_h, lg_src, lg_dst, WT2, M, PART);
    hipMemsetAsync(STAT, 0, 512 * sizeof(float), stream);
    k_reduce_part<<<dim3(1, 32), 256, 0, stream>>>(PART, N_ANGLESC / 64, 160, STAT);
    k_finalize<<<1, 256, 0, stream>>>(STAT, c2_bnm_g + i * 80, c2_bnm_b + i * 80, SCSHM, 80, 1.f / N_ANGLESC);
    k_gather2<<<cdiv((long long)N_EDGESC * EFDIM, 256), 256, 0, stream>>>(M, PERM2, OFF2, SCSHM, HAGG2);
    hipMemsetAsync(STAT, 0, 512 * sizeof(float), stream);
    k_colstats_rmb<<<1024, 64, 0, stream>>>(HAGG2, (long long)N_EDGESC, 40, STAT);
    k_finalize<<<1, 256, 0, stream>>>(STAT, c2_bn_g + i * 40, c2_bn_b + i * 40, SCSHN, 40, 1.f / N_EDGESC);
    k_bn_residual_bb<<<cdiv((long long)N_EDGESC * EFDIM, 256), 256, 0, stream>>>(
        EF, HAGG2, SCSHN, N_EDGESC * EFDIM, EFDIM);
  }

  // ---------- readout ----------
  k_head<<<N_GRAPHSC, 256, 0, stream>>>(NF, node_gid, fc_W, fc_b, out_W, out_b, (float*)d_out);
}